// Round 1
// baseline (2993.840 us; speedup 1.0000x reference)
//
#include <hip/hip_runtime.h>
#include <cstddef>

#define EPSF 1e-6f

constexpr int D   = 1024;
constexpr int Bv  = 2;
constexpr int S   = 2048;
constexpr int M   = Bv * S;    // 4096 rows total
constexpr int CH  = 128;       // chunk
constexpr int NCH = S / CH;    // 16 chunks

__device__ __forceinline__ float elu1(float x) {
    // jax.nn.elu(x)+1 with alpha=1: x>0 ? x+1 : exp(x)
    return x > 0.f ? x + 1.f : __expf(x);
}
__device__ __forceinline__ float sigmoidf_(float x) {
    return 1.f / (1.f + __expf(-x));
}
__device__ __forceinline__ float wave_reduce(float x) {
#pragma unroll
    for (int off = 32; off > 0; off >>= 1) x += __shfl_down(x, off);
    return x;
}

// 16 FMAs per kk from two LDS b128 reads (uses acc, ty, tx from scope)
#define COMPUTE16(AS, BS)                                                  \
    _Pragma("unroll")                                                      \
    for (int kk = 0; kk < 16; ++kk) {                                      \
        float4 av = *(const float4*)&AS[kk][ty << 2];                      \
        float4 bv = *(const float4*)&BS[kk][tx << 2];                      \
        acc[0][0] += av.x * bv.x; acc[0][1] += av.x * bv.y;                \
        acc[0][2] += av.x * bv.z; acc[0][3] += av.x * bv.w;                \
        acc[1][0] += av.y * bv.x; acc[1][1] += av.y * bv.y;                \
        acc[1][2] += av.y * bv.z; acc[1][3] += av.y * bv.w;                \
        acc[2][0] += av.z * bv.x; acc[2][1] += av.z * bv.y;                \
        acc[2][2] += av.z * bv.z; acc[2][3] += av.z * bv.w;                \
        acc[3][0] += av.w * bv.x; acc[3][1] += av.w * bv.y;                \
        acc[3][2] += av.w * bv.z; acc[3][3] += av.w * bv.w;                \
    }

// C[M,N] = A[M,K] @ B[N,K]^T, row-major; mode 1 applies elu+1 on store.
__global__ __launch_bounds__(256) void gemm_bt(const float* __restrict__ A,
                                               const float* __restrict__ B,
                                               float* __restrict__ C,
                                               int Mm, int Nn, int Kk, int mode)
{
    __shared__ float As[16][68];
    __shared__ float Bs[16][68];
    const int tid = threadIdx.x;
    const int m0 = blockIdx.y * 64;
    const int n0 = blockIdx.x * 64;
    const int lm = tid >> 2;            // 0..63
    const int lk = (tid & 3) << 2;      // 0,4,8,12
    const int ty = tid >> 4;            // 0..15
    const int tx = tid & 15;            // 0..15

    const float* Arow = A + (size_t)(m0 + lm) * Kk + lk;
    const float* Brow = B + (size_t)(n0 + lm) * Kk + lk;

    float acc[4][4] = {};
    for (int k0 = 0; k0 < Kk; k0 += 16) {
        float4 a4 = *(const float4*)(Arow + k0);
        float4 b4 = *(const float4*)(Brow + k0);
        __syncthreads();
        As[lk + 0][lm] = a4.x; As[lk + 1][lm] = a4.y;
        As[lk + 2][lm] = a4.z; As[lk + 3][lm] = a4.w;
        Bs[lk + 0][lm] = b4.x; Bs[lk + 1][lm] = b4.y;
        Bs[lk + 2][lm] = b4.z; Bs[lk + 3][lm] = b4.w;
        __syncthreads();
        COMPUTE16(As, Bs)
    }
#pragma unroll
    for (int ii = 0; ii < 4; ++ii) {
        int row = m0 + (ty << 2) + ii;
        float4 o = make_float4(acc[ii][0], acc[ii][1], acc[ii][2], acc[ii][3]);
        if (mode == 1) { o.x = elu1(o.x); o.y = elu1(o.y); o.z = elu1(o.z); o.w = elu1(o.w); }
        *(float4*)(C + (size_t)row * Nn + n0 + (tx << 2)) = o;
    }
}

// C[M,N] = A[M,K] @ B[K,N]  (B row-major, K-major — direct row staging)
__global__ __launch_bounds__(256) void gemm_bn(const float* __restrict__ A,
                                               const float* __restrict__ B,
                                               float* __restrict__ C,
                                               int Mm, int Nn, int Kk)
{
    __shared__ float As[16][68];
    __shared__ float Bs[16][68];
    const int tid = threadIdx.x;
    const int m0 = blockIdx.y * 64;
    const int n0 = blockIdx.x * 64;
    const int lm = tid >> 2;
    const int lk = (tid & 3) << 2;
    const int kk2 = tid >> 4;           // 0..15 (k row in tile)
    const int e4  = (tid & 15) << 2;    // col*4
    const int ty = tid >> 4;
    const int tx = tid & 15;

    float acc[4][4] = {};
    for (int k0 = 0; k0 < Kk; k0 += 16) {
        float4 a4 = *(const float4*)(A + (size_t)(m0 + lm) * Kk + k0 + lk);
        float4 b4 = *(const float4*)(B + (size_t)(k0 + kk2) * Nn + n0 + e4);
        __syncthreads();
        As[lk + 0][lm] = a4.x; As[lk + 1][lm] = a4.y;
        As[lk + 2][lm] = a4.z; As[lk + 3][lm] = a4.w;
        *(float4*)&Bs[kk2][e4] = b4;
        __syncthreads();
        COMPUTE16(As, Bs)
    }
#pragma unroll
    for (int ii = 0; ii < 4; ++ii) {
        int row = m0 + (ty << 2) + ii;
        float4 o = make_float4(acc[ii][0], acc[ii][1], acc[ii][2], acc[ii][3]);
        *(float4*)(C + (size_t)row * Nn + n0 + (tx << 2)) = o;
    }
}

// comb[row,:] *= g*active / clip(sq_row . mnorm, EPS)
__global__ __launch_bounds__(256) void mem_combine(const float* __restrict__ sq,
                                                   const float* __restrict__ mnorm,
                                                   const float* __restrict__ gate,
                                                   float* __restrict__ comb)
{
    const int wave = threadIdx.x >> 6;
    const int lane = threadIdx.x & 63;
    const int row  = blockIdx.x * 4 + wave;
    const float* sr = sq + (size_t)row * D;
    float dot = 0.f, msum = 0.f;
    for (int d = lane; d < D; d += 64) {
        float mn = mnorm[d];
        dot  += sr[d] * mn;
        msum += mn;
    }
    dot  = wave_reduce(dot);
    msum = wave_reduce(msum);
    dot  = __shfl(dot, 0);
    msum = __shfl(msum, 0);
    const float g = sigmoidf_(gate[0]);
    const float active = (msum >= EPSF) ? 1.f : 0.f;
    const float scale = g * active / fmaxf(dot, EPSF);
    float* cr = comb + (size_t)row * D;
    for (int e = lane; e < D; e += 64) cr[e] *= scale;
}

// A_c = (sq_c @ sk_c^T) * tril  -> Abuf[b][128][128]
__global__ __launch_bounds__(256) void attn_scores(const float* __restrict__ sq,
                                                   const float* __restrict__ sk,
                                                   float* __restrict__ Abuf, int c)
{
    __shared__ float As[16][68];
    __shared__ float Bs[16][68];
    const int tid = threadIdx.x;
    const int b = blockIdx.z;
    const int m0 = blockIdx.y * 64;
    const int n0 = blockIdx.x * 64;
    const int lm = tid >> 2;
    const int lk = (tid & 3) << 2;
    const int ty = tid >> 4;
    const int tx = tid & 15;

    const float* Ap = sq + ((size_t)b * S + (size_t)c * CH) * D;
    const float* Bp = sk + ((size_t)b * S + (size_t)c * CH) * D;
    float* Cp = Abuf + (size_t)b * CH * CH;

    float acc[4][4] = {};
    for (int k0 = 0; k0 < D; k0 += 16) {
        float4 a4 = *(const float4*)(Ap + (size_t)(m0 + lm) * D + k0 + lk);
        float4 b4 = *(const float4*)(Bp + (size_t)(n0 + lm) * D + k0 + lk);
        __syncthreads();
        As[lk + 0][lm] = a4.x; As[lk + 1][lm] = a4.y;
        As[lk + 2][lm] = a4.z; As[lk + 3][lm] = a4.w;
        Bs[lk + 0][lm] = b4.x; Bs[lk + 1][lm] = b4.y;
        Bs[lk + 2][lm] = b4.z; Bs[lk + 3][lm] = b4.w;
        __syncthreads();
        COMPUTE16(As, Bs)
    }
#pragma unroll
    for (int ii = 0; ii < 4; ++ii) {
        int row = m0 + (ty << 2) + ii;
        float4 o;
        int colb = n0 + (tx << 2);
        o.x = (colb + 0 <= row) ? acc[ii][0] : 0.f;
        o.y = (colb + 1 <= row) ? acc[ii][1] : 0.f;
        o.z = (colb + 2 <= row) ? acc[ii][2] : 0.f;
        o.w = (colb + 3 <= row) ? acc[ii][3] : 0.f;
        *(float4*)(Cp + (size_t)row * CH + colb) = o;
    }
}

// den[b,i] = rowsum(A_c[b,i,:]) + sq_row . z[b]
__global__ __launch_bounds__(256) void attn_den(const float* __restrict__ Abuf,
                                                const float* __restrict__ sq,
                                                const float* __restrict__ z,
                                                float* __restrict__ den, int c)
{
    const int wave = threadIdx.x >> 6;
    const int lane = threadIdx.x & 63;
    const int idx = blockIdx.x * 4 + wave;   // 0 .. B*CH-1
    const int b = idx / CH;
    const int i = idx % CH;
    const float* Ar = Abuf + ((size_t)b * CH + i) * CH;
    float s = 0.f;
    for (int j = lane; j < CH; j += 64) s += Ar[j];
    const float* Sq = sq + ((size_t)b * S + (size_t)c * CH + i) * D;
    const float* zb = z + (size_t)b * D;
    for (int d = lane; d < D; d += 64) s += Sq[d] * zb[d];
    s = wave_reduce(s);
    if (lane == 0) den[idx] = s;
}

// comb[row,:] += (1-g) * (A_c@v_c + sq_c@Skv) / clip(den, EPS)
__global__ __launch_bounds__(256) void attn_out(const float* __restrict__ Abuf,
                                                const float* __restrict__ vbuf,
                                                const float* __restrict__ sq,
                                                const float* __restrict__ Skv,
                                                const float* __restrict__ den,
                                                const float* __restrict__ gate,
                                                float* __restrict__ comb, int c)
{
    __shared__ float As[16][68];
    __shared__ float Bs[16][68];
    const int tid = threadIdx.x;
    const int b  = blockIdx.z;
    const int i0 = blockIdx.y * 64;      // chunk-row tile (0 or 64)
    const int e0 = blockIdx.x * 64;      // out-col tile
    const int lm = tid >> 2;
    const int lk = (tid & 3) << 2;
    const int kk2 = tid >> 4;
    const int e4  = (tid & 15) << 2;
    const int ty = tid >> 4;
    const int tx = tid & 15;

    const float* Ab = Abuf + (size_t)b * CH * CH;
    const float* Vb = vbuf + ((size_t)b * S + (size_t)c * CH) * D;
    const float* Sq = sq   + ((size_t)b * S + (size_t)c * CH) * D;
    const float* Sm = Skv  + (size_t)b * D * D;

    float acc[4][4] = {};
    // phase 1: K=128, A_c @ v_c
    for (int k0 = 0; k0 < CH; k0 += 16) {
        float4 a4 = *(const float4*)(Ab + (size_t)(i0 + lm) * CH + k0 + lk);
        float4 b4 = *(const float4*)(Vb + (size_t)(k0 + kk2) * D + e0 + e4);
        __syncthreads();
        As[lk + 0][lm] = a4.x; As[lk + 1][lm] = a4.y;
        As[lk + 2][lm] = a4.z; As[lk + 3][lm] = a4.w;
        *(float4*)&Bs[kk2][e4] = b4;
        __syncthreads();
        COMPUTE16(As, Bs)
    }
    // phase 2: K=1024, sq_c @ Skv
    for (int k0 = 0; k0 < D; k0 += 16) {
        float4 a4 = *(const float4*)(Sq + (size_t)(i0 + lm) * D + k0 + lk);
        float4 b4 = *(const float4*)(Sm + (size_t)(k0 + kk2) * D + e0 + e4);
        __syncthreads();
        As[lk + 0][lm] = a4.x; As[lk + 1][lm] = a4.y;
        As[lk + 2][lm] = a4.z; As[lk + 3][lm] = a4.w;
        *(float4*)&Bs[kk2][e4] = b4;
        __syncthreads();
        COMPUTE16(As, Bs)
    }
    const float g = sigmoidf_(gate[0]);
    const float wloc = 1.f - g;
#pragma unroll
    for (int ii = 0; ii < 4; ++ii) {
        int i = i0 + (ty << 2) + ii;
        float inv = wloc / fmaxf(den[b * CH + i], EPSF);
        float* cp = comb + ((size_t)b * S + (size_t)c * CH + i) * D + e0 + (tx << 2);
        float4 cur = *(float4*)cp;
        cur.x += acc[ii][0] * inv; cur.y += acc[ii][1] * inv;
        cur.z += acc[ii][2] * inv; cur.w += acc[ii][3] * inv;
        *(float4*)cp = cur;
    }
}

// Skv[b] += sk_c^T @ v_c ; z[b] += colsum(sk_c)
__global__ __launch_bounds__(256) void attn_update(const float* __restrict__ sk,
                                                   const float* __restrict__ vbuf,
                                                   float* __restrict__ Skv,
                                                   float* __restrict__ z, int c)
{
    __shared__ float Ks[16][68];
    __shared__ float Vs[16][68];
    const int tid = threadIdx.x;
    const int b  = blockIdx.z;
    const int d0 = blockIdx.y * 64;
    const int e0 = blockIdx.x * 64;
    const int kk2 = tid >> 4;
    const int e4  = (tid & 15) << 2;
    const int ty = tid >> 4;
    const int tx = tid & 15;

    const float* Kb = sk   + ((size_t)b * S + (size_t)c * CH) * D;
    const float* Vb = vbuf + ((size_t)b * S + (size_t)c * CH) * D;

    float acc[4][4] = {};
    for (int k0 = 0; k0 < CH; k0 += 16) {
        float4 a4 = *(const float4*)(Kb + (size_t)(k0 + kk2) * D + d0 + e4);
        float4 b4 = *(const float4*)(Vb + (size_t)(k0 + kk2) * D + e0 + e4);
        __syncthreads();
        *(float4*)&Ks[kk2][e4] = a4;
        *(float4*)&Vs[kk2][e4] = b4;
        __syncthreads();
        COMPUTE16(Ks, Vs)
    }
    float* Sp = Skv + (size_t)b * D * D;
#pragma unroll
    for (int ii = 0; ii < 4; ++ii) {
        float* p = Sp + (size_t)(d0 + (ty << 2) + ii) * D + e0 + (tx << 2);
        float4 cur = *(float4*)p;
        cur.x += acc[ii][0]; cur.y += acc[ii][1];
        cur.z += acc[ii][2]; cur.w += acc[ii][3];
        *(float4*)p = cur;
    }
    if (blockIdx.x == 0 && tid < 64) {
        int d = d0 + tid;
        float s = 0.f;
        for (int m = 0; m < CH; ++m) s += Kb[(size_t)m * D + d];
        z[(size_t)b * D + d] += s;
    }
}

extern "C" void kernel_launch(void* const* d_in, const int* in_sizes, int n_in,
                              void* d_out, int out_size, void* d_ws, size_t ws_size,
                              hipStream_t stream)
{
    const float* h      = (const float*)d_in[0];
    const float* w_q    = (const float*)d_in[1];
    const float* w_k    = (const float*)d_in[2];
    const float* w_v    = (const float*)d_in[3];
    const float* w_o    = (const float*)d_in[4];
    const float* gate   = (const float*)d_in[5];
    const float* memory = (const float*)d_in[6];
    const float* mnorm  = (const float*)d_in[7];
    float* out = (float*)d_out;

    // workspace layout (floats): ~72 MiB total
    float* ws   = (float*)d_ws;
    float* sq   = ws;                               // M*D
    float* sk   = sq   + (size_t)M * D;             // M*D
    float* v    = sk   + (size_t)M * D;             // M*D
    float* comb = v    + (size_t)M * D;             // M*D
    float* Skv  = comb + (size_t)M * D;             // B*D*D
    float* z    = Skv  + (size_t)Bv * D * D;        // B*D
    float* Abuf = z    + (size_t)Bv * D;            // B*CH*CH
    float* den  = Abuf + (size_t)Bv * CH * CH;      // B*CH

    hipMemsetAsync(Skv, 0, (size_t)Bv * D * D * sizeof(float), stream);
    hipMemsetAsync(z,   0, (size_t)Bv * D * sizeof(float), stream);

    dim3 blk(256);
    dim3 gproj(D / 64, M / 64);  // (16, 64)
    gemm_bt<<<gproj, blk, 0, stream>>>(h, w_q, sq, M, D, D, 1);  // sq = elu1(h@Wq^T)
    gemm_bt<<<gproj, blk, 0, stream>>>(h, w_k, sk, M, D, D, 1);  // sk = elu1(h@Wk^T)
    gemm_bt<<<gproj, blk, 0, stream>>>(h, w_v, v,  M, D, D, 0);  // v  = h@Wv^T
    gemm_bn<<<gproj, blk, 0, stream>>>(sq, memory, comb, M, D, D);   // comb = sq@memory
    mem_combine<<<M / 4, blk, 0, stream>>>(sq, mnorm, gate, comb);   // comb = g*active*comb/norm

    for (int c = 0; c < NCH; ++c) {
        attn_scores<<<dim3(2, 2, Bv), blk, 0, stream>>>(sq, sk, Abuf, c);
        attn_den<<<(Bv * CH) / 4, blk, 0, stream>>>(Abuf, sq, z, den, c);
        attn_out<<<dim3(D / 64, CH / 64, Bv), blk, 0, stream>>>(Abuf, v, sq, Skv, den, gate, comb, c);
        attn_update<<<dim3(D / 64, D / 64, Bv), blk, 0, stream>>>(sk, v, Skv, z, c);
    }

    gemm_bt<<<gproj, blk, 0, stream>>>(comb, w_o, out, M, D, D, 0);  // out = comb@Wo^T
}

// Round 2
// 1103.676 us; speedup vs baseline: 2.7126x; 2.7126x over previous
//
#include <hip/hip_runtime.h>
#include <cstddef>

#define EPSF 1e-6f

constexpr int D   = 1024;
constexpr int Bv  = 2;
constexpr int S   = 2048;
constexpr int M   = Bv * S;    // 4096 rows total
constexpr int CH  = 256;       // chunk (math exact for any chunking)
constexpr int NCH = S / CH;    // 8 chunks

__device__ __forceinline__ float elu1(float x) {
    return x > 0.f ? x + 1.f : __expf(x);
}
__device__ __forceinline__ float sigmoidf_(float x) {
    return 1.f / (1.f + __expf(-x));
}
__device__ __forceinline__ float wave_reduce(float x) {
#pragma unroll
    for (int off = 32; off > 0; off >>= 1) x += __shfl_down(x, off);
    return x;
}
__device__ __forceinline__ unsigned short f2bf(float x) {
    unsigned u = __float_as_uint(x);
    return (unsigned short)((u + 0x7fffu + ((u >> 16) & 1u)) >> 16);
}
__device__ __forceinline__ float bf2f(unsigned short h) {
    return __uint_as_float(((unsigned)h) << 16);
}

// 16 FMAs per kk from two LDS b128 reads (uses acc, ty, tx from scope)
#define COMPUTE16(AS, BS)                                                  \
    _Pragma("unroll")                                                      \
    for (int kk = 0; kk < 16; ++kk) {                                      \
        float4 av = *(const float4*)&AS[kk][ty << 2];                      \
        float4 bv = *(const float4*)&BS[kk][tx << 2];                      \
        acc[0][0] += av.x * bv.x; acc[0][1] += av.x * bv.y;                \
        acc[0][2] += av.x * bv.z; acc[0][3] += av.x * bv.w;                \
        acc[1][0] += av.y * bv.x; acc[1][1] += av.y * bv.y;                \
        acc[1][2] += av.y * bv.z; acc[1][3] += av.y * bv.w;                \
        acc[2][0] += av.z * bv.x; acc[2][1] += av.z * bv.y;                \
        acc[2][2] += av.z * bv.z; acc[2][3] += av.z * bv.w;                \
        acc[3][0] += av.w * bv.x; acc[3][1] += av.w * bv.y;                \
        acc[3][2] += av.w * bv.z; acc[3][3] += av.w * bv.w;                \
    }

// C[M,N] = A[M,K] @ B[N,K]^T, row-major; mode 1 applies elu+1 on store.
__global__ __launch_bounds__(256) void gemm_bt(const float* __restrict__ A,
                                               const float* __restrict__ B,
                                               float* __restrict__ C,
                                               int Mm, int Nn, int Kk, int mode)
{
    __shared__ float As[16][68];
    __shared__ float Bs[16][68];
    const int tid = threadIdx.x;
    const int m0 = blockIdx.y * 64;
    const int n0 = blockIdx.x * 64;
    const int lm = tid >> 2;
    const int lk = (tid & 3) << 2;
    const int ty = tid >> 4;
    const int tx = tid & 15;

    const float* Arow = A + (size_t)(m0 + lm) * Kk + lk;
    const float* Brow = B + (size_t)(n0 + lm) * Kk + lk;

    float acc[4][4] = {};
    for (int k0 = 0; k0 < Kk; k0 += 16) {
        float4 a4 = *(const float4*)(Arow + k0);
        float4 b4 = *(const float4*)(Brow + k0);
        __syncthreads();
        As[lk + 0][lm] = a4.x; As[lk + 1][lm] = a4.y;
        As[lk + 2][lm] = a4.z; As[lk + 3][lm] = a4.w;
        Bs[lk + 0][lm] = b4.x; Bs[lk + 1][lm] = b4.y;
        Bs[lk + 2][lm] = b4.z; Bs[lk + 3][lm] = b4.w;
        __syncthreads();
        COMPUTE16(As, Bs)
    }
#pragma unroll
    for (int ii = 0; ii < 4; ++ii) {
        int row = m0 + (ty << 2) + ii;
        float4 o = make_float4(acc[ii][0], acc[ii][1], acc[ii][2], acc[ii][3]);
        if (mode == 1) { o.x = elu1(o.x); o.y = elu1(o.y); o.z = elu1(o.z); o.w = elu1(o.w); }
        *(float4*)(C + (size_t)row * Nn + n0 + (tx << 2)) = o;
    }
}

// C[M,N] = A[M,K] @ B[K,N]  (B row-major, K-major)
__global__ __launch_bounds__(256) void gemm_bn(const float* __restrict__ A,
                                               const float* __restrict__ B,
                                               float* __restrict__ C,
                                               int Mm, int Nn, int Kk)
{
    __shared__ float As[16][68];
    __shared__ float Bs[16][68];
    const int tid = threadIdx.x;
    const int m0 = blockIdx.y * 64;
    const int n0 = blockIdx.x * 64;
    const int lm = tid >> 2;
    const int lk = (tid & 3) << 2;
    const int kk2 = tid >> 4;
    const int e4  = (tid & 15) << 2;
    const int ty = tid >> 4;
    const int tx = tid & 15;

    float acc[4][4] = {};
    for (int k0 = 0; k0 < Kk; k0 += 16) {
        float4 a4 = *(const float4*)(A + (size_t)(m0 + lm) * Kk + k0 + lk);
        float4 b4 = *(const float4*)(B + (size_t)(k0 + kk2) * Nn + n0 + e4);
        __syncthreads();
        As[lk + 0][lm] = a4.x; As[lk + 1][lm] = a4.y;
        As[lk + 2][lm] = a4.z; As[lk + 3][lm] = a4.w;
        *(float4*)&Bs[kk2][e4] = b4;
        __syncthreads();
        COMPUTE16(As, Bs)
    }
#pragma unroll
    for (int ii = 0; ii < 4; ++ii) {
        int row = m0 + (ty << 2) + ii;
        float4 o = make_float4(acc[ii][0], acc[ii][1], acc[ii][2], acc[ii][3]);
        *(float4*)(C + (size_t)row * Nn + n0 + (tx << 2)) = o;
    }
}

// comb[row,:] *= g*active / clip(sq_row . mnorm, EPS)
__global__ __launch_bounds__(256) void mem_combine(const float* __restrict__ sq,
                                                   const float* __restrict__ mnorm,
                                                   const float* __restrict__ gate,
                                                   float* __restrict__ comb)
{
    const int wave = threadIdx.x >> 6;
    const int lane = threadIdx.x & 63;
    const int row  = blockIdx.x * 4 + wave;
    const float* sr = sq + (size_t)row * D;
    float dot = 0.f, msum = 0.f;
    for (int d = lane; d < D; d += 64) {
        float mn = mnorm[d];
        dot  += sr[d] * mn;
        msum += mn;
    }
    dot  = wave_reduce(dot);
    msum = wave_reduce(msum);
    dot  = __shfl(dot, 0);
    msum = __shfl(msum, 0);
    const float g = sigmoidf_(gate[0]);
    const float active = (msum >= EPSF) ? 1.f : 0.f;
    const float scale = g * active / fmaxf(dot, EPSF);
    float* cr = comb + (size_t)row * D;
    for (int e = lane; e < D; e += 64) cr[e] *= scale;
}

// Per-chunk KV state: Pst[b][c] = sk_c^T @ v_c (bf16), zst[b][c] = colsum(sk_c)
__global__ __launch_bounds__(256) void chunk_kv(const float* __restrict__ sk,
                                                const float* __restrict__ vbuf,
                                                unsigned short* __restrict__ Pst,
                                                float* __restrict__ zst)
{
    __shared__ float Ks[16][68];
    __shared__ float Vs[16][68];
    const int tid = threadIdx.x;
    const int bc = blockIdx.z;           // b*NCH + c
    const int b  = bc / NCH;
    const int c  = bc % NCH;
    const int d0 = blockIdx.y * 64;
    const int e0 = blockIdx.x * 64;
    const int kk2 = tid >> 4;
    const int e4  = (tid & 15) << 2;
    const int ty = tid >> 4;
    const int tx = tid & 15;

    const float* Kb = sk   + ((size_t)b * S + (size_t)c * CH) * D;
    const float* Vb = vbuf + ((size_t)b * S + (size_t)c * CH) * D;

    float acc[4][4] = {};
    for (int k0 = 0; k0 < CH; k0 += 16) {
        float4 a4 = *(const float4*)(Kb + (size_t)(k0 + kk2) * D + d0 + e4);
        float4 b4 = *(const float4*)(Vb + (size_t)(k0 + kk2) * D + e0 + e4);
        __syncthreads();
        *(float4*)&Ks[kk2][e4] = a4;
        *(float4*)&Vs[kk2][e4] = b4;
        __syncthreads();
        COMPUTE16(Ks, Vs)
    }
    unsigned short* Pp = Pst + (size_t)bc * D * D;
#pragma unroll
    for (int ii = 0; ii < 4; ++ii) {
        ushort4 o;
        o.x = f2bf(acc[ii][0]); o.y = f2bf(acc[ii][1]);
        o.z = f2bf(acc[ii][2]); o.w = f2bf(acc[ii][3]);
        *(ushort4*)(Pp + (size_t)(d0 + (ty << 2) + ii) * D + e0 + (tx << 2)) = o;
    }
    if (blockIdx.x == 0 && tid < 64) {
        int d = d0 + tid;
        float s = 0.f;
        for (int m = 0; m < CH; ++m) s += Kb[(size_t)m * D + d];
        zst[(size_t)bc * D + d] = s;
    }
}

// In-place exclusive prefix over chunks: Pst[b][c] <- sum_{j<c} Pst_chunk[b][j]
__global__ __launch_bounds__(256) void scan_P(unsigned short* __restrict__ Pst)
{
    const size_t g = (size_t)blockIdx.x * 256 + threadIdx.x;   // 0 .. B*D*D-1
    const int b = (int)(g / ((size_t)D * D));
    const size_t idx = g % ((size_t)D * D);
    unsigned short* p = Pst + (size_t)b * NCH * D * D + idx;
    float acc = 0.f;
#pragma unroll
    for (int c = 0; c < NCH; ++c) {
        unsigned short* q = p + (size_t)c * D * D;
        float tmp = bf2f(*q);
        *q = f2bf(acc);
        acc += tmp;
    }
}

// In-place exclusive prefix over chunks for z
__global__ __launch_bounds__(256) void scan_z(float* __restrict__ zst)
{
    const int g = blockIdx.x * 256 + threadIdx.x;   // 0 .. B*D-1
    const int b = g / D;
    const int d = g % D;
    float* p = zst + (size_t)b * NCH * D + d;
    float acc = 0.f;
#pragma unroll
    for (int c = 0; c < NCH; ++c) {
        float tmp = p[(size_t)c * D];
        p[(size_t)c * D] = acc;
        acc += tmp;
    }
}

// A[b][c] = (sq_c @ sk_c^T) * tril, all chunks in one dispatch
__global__ __launch_bounds__(256) void attn_scores_all(const float* __restrict__ sq,
                                                       const float* __restrict__ sk,
                                                       float* __restrict__ Abuf)
{
    const int tid = threadIdx.x;
    const int bc = blockIdx.z;
    const int b  = bc / NCH;
    const int c  = bc % NCH;
    const int m0 = blockIdx.y * 64;
    const int n0 = blockIdx.x * 64;
    const int ty = tid >> 4;
    const int tx = tid & 15;
    float* Cp = Abuf + (size_t)bc * CH * CH;

    if (n0 > m0 + 63) {   // fully above diagonal: zero, skip K-loop
#pragma unroll
        for (int ii = 0; ii < 4; ++ii) {
            int row = m0 + (ty << 2) + ii;
            *(float4*)(Cp + (size_t)row * CH + n0 + (tx << 2)) =
                make_float4(0.f, 0.f, 0.f, 0.f);
        }
        return;
    }

    __shared__ float As[16][68];
    __shared__ float Bs[16][68];
    const int lm = tid >> 2;
    const int lk = (tid & 3) << 2;
    const float* Ap = sq + ((size_t)b * S + (size_t)c * CH) * D;
    const float* Bp = sk + ((size_t)b * S + (size_t)c * CH) * D;

    float acc[4][4] = {};
    for (int k0 = 0; k0 < D; k0 += 16) {
        float4 a4 = *(const float4*)(Ap + (size_t)(m0 + lm) * D + k0 + lk);
        float4 b4 = *(const float4*)(Bp + (size_t)(n0 + lm) * D + k0 + lk);
        __syncthreads();
        As[lk + 0][lm] = a4.x; As[lk + 1][lm] = a4.y;
        As[lk + 2][lm] = a4.z; As[lk + 3][lm] = a4.w;
        Bs[lk + 0][lm] = b4.x; Bs[lk + 1][lm] = b4.y;
        Bs[lk + 2][lm] = b4.z; Bs[lk + 3][lm] = b4.w;
        __syncthreads();
        COMPUTE16(As, Bs)
    }
#pragma unroll
    for (int ii = 0; ii < 4; ++ii) {
        int row = m0 + (ty << 2) + ii;
        int colb = n0 + (tx << 2);
        float4 o;
        o.x = (colb + 0 <= row) ? acc[ii][0] : 0.f;
        o.y = (colb + 1 <= row) ? acc[ii][1] : 0.f;
        o.z = (colb + 2 <= row) ? acc[ii][2] : 0.f;
        o.w = (colb + 3 <= row) ? acc[ii][3] : 0.f;
        *(float4*)(Cp + (size_t)row * CH + colb) = o;
    }
}

// den[r] = rowsum(A) + sq_r . z_prefix  for all rows in one dispatch
__global__ __launch_bounds__(256) void attn_den_all(const float* __restrict__ Abuf,
                                                    const float* __restrict__ sq,
                                                    const float* __restrict__ zst,
                                                    float* __restrict__ den)
{
    const int wave = threadIdx.x >> 6;
    const int lane = threadIdx.x & 63;
    const int r = blockIdx.x * 4 + wave;   // 0 .. B*S-1
    const int b = r / S;
    const int sr = r % S;
    const int c = sr / CH;
    const int i = sr % CH;
    const float* Ar = Abuf + ((size_t)(b * NCH + c) * CH + i) * CH;
    float s = 0.f;
    for (int j = lane; j < CH; j += 64) s += Ar[j];
    const float* Sq = sq + (size_t)r * D;
    const float* zb = zst + (size_t)(b * NCH + c) * D;
    for (int d = lane; d < D; d += 64) s += Sq[d] * zb[d];
    s = wave_reduce(s);
    if (lane == 0) den[r] = s;
}

// comb[r,:] += (1-g) * (A@v + sq@P_prefix) / clip(den, EPS), all chunks
__global__ __launch_bounds__(256) void attn_out_all(const float* __restrict__ Abuf,
                                                    const float* __restrict__ vbuf,
                                                    const float* __restrict__ sq,
                                                    const unsigned short* __restrict__ Pst,
                                                    const float* __restrict__ den,
                                                    const float* __restrict__ gate,
                                                    float* __restrict__ comb)
{
    __shared__ float As[16][68];
    __shared__ float Bs[16][68];
    const int tid = threadIdx.x;
    const int bc = blockIdx.z;
    const int b  = bc / NCH;
    const int c  = bc % NCH;
    const int i0 = blockIdx.y * 64;
    const int e0 = blockIdx.x * 64;
    const int lm = tid >> 2;
    const int lk = (tid & 3) << 2;
    const int kk2 = tid >> 4;
    const int e4  = (tid & 15) << 2;
    const int ty = tid >> 4;
    const int tx = tid & 15;

    const float* Ab = Abuf + (size_t)bc * CH * CH;
    const float* Vb = vbuf + ((size_t)b * S + (size_t)c * CH) * D;
    const float* Sq = sq   + ((size_t)b * S + (size_t)c * CH) * D;
    const unsigned short* Pp = Pst + (size_t)bc * D * D;

    float acc[4][4] = {};
    // phase 1: K=CH, A @ v_c
    for (int k0 = 0; k0 < CH; k0 += 16) {
        float4 a4 = *(const float4*)(Ab + (size_t)(i0 + lm) * CH + k0 + lk);
        float4 b4 = *(const float4*)(Vb + (size_t)(k0 + kk2) * D + e0 + e4);
        __syncthreads();
        As[lk + 0][lm] = a4.x; As[lk + 1][lm] = a4.y;
        As[lk + 2][lm] = a4.z; As[lk + 3][lm] = a4.w;
        *(float4*)&Bs[kk2][e4] = b4;
        __syncthreads();
        COMPUTE16(As, Bs)
    }
    // phase 2: K=D, sq_c @ P_prefix (bf16 B)
    for (int k0 = 0; k0 < D; k0 += 16) {
        float4 a4 = *(const float4*)(Sq + (size_t)(i0 + lm) * D + k0 + lk);
        ushort4 b4u = *(const ushort4*)(Pp + (size_t)(k0 + kk2) * D + e0 + e4);
        __syncthreads();
        As[lk + 0][lm] = a4.x; As[lk + 1][lm] = a4.y;
        As[lk + 2][lm] = a4.z; As[lk + 3][lm] = a4.w;
        Bs[kk2][e4 + 0] = bf2f(b4u.x);
        Bs[kk2][e4 + 1] = bf2f(b4u.y);
        Bs[kk2][e4 + 2] = bf2f(b4u.z);
        Bs[kk2][e4 + 3] = bf2f(b4u.w);
        __syncthreads();
        COMPUTE16(As, Bs)
    }
    const float g = sigmoidf_(gate[0]);
    const float wloc = 1.f - g;
#pragma unroll
    for (int ii = 0; ii < 4; ++ii) {
        int i = i0 + (ty << 2) + ii;
        int r = b * S + c * CH + i;
        float inv = wloc / fmaxf(den[r], EPSF);
        float* cp = comb + (size_t)r * D + e0 + (tx << 2);
        float4 cur = *(float4*)cp;
        cur.x += acc[ii][0] * inv; cur.y += acc[ii][1] * inv;
        cur.z += acc[ii][2] * inv; cur.w += acc[ii][3] * inv;
        *(float4*)cp = cur;
    }
}

extern "C" void kernel_launch(void* const* d_in, const int* in_sizes, int n_in,
                              void* d_out, int out_size, void* d_ws, size_t ws_size,
                              hipStream_t stream)
{
    const float* h      = (const float*)d_in[0];
    const float* w_q    = (const float*)d_in[1];
    const float* w_k    = (const float*)d_in[2];
    const float* w_v    = (const float*)d_in[3];
    const float* w_o    = (const float*)d_in[4];
    const float* gate   = (const float*)d_in[5];
    const float* memory = (const float*)d_in[6];
    const float* mnorm  = (const float*)d_in[7];
    float* out = (float*)d_out;

    // workspace layout: 4x M*D f32 (64MB) + Abuf 4MB + P states bf16 32MB + small
    float* ws   = (float*)d_ws;
    float* sq   = ws;                               // M*D
    float* sk   = sq   + (size_t)M * D;             // M*D
    float* v    = sk   + (size_t)M * D;             // M*D
    float* comb = v    + (size_t)M * D;             // M*D
    float* Abuf = comb + (size_t)M * D;             // B*NCH*CH*CH (1M floats)
    float* den  = Abuf + (size_t)Bv * NCH * CH * CH;        // B*S
    float* zst  = den  + (size_t)Bv * S;                    // B*NCH*D
    unsigned short* Pst = (unsigned short*)(zst + (size_t)Bv * NCH * D);  // B*NCH*D*D bf16

    dim3 blk(256);
    dim3 gproj(D / 64, M / 64);  // (16, 64)
    gemm_bt<<<gproj, blk, 0, stream>>>(h, w_q, sq, M, D, D, 1);  // sq = elu1(h@Wq^T)
    gemm_bt<<<gproj, blk, 0, stream>>>(h, w_k, sk, M, D, D, 1);  // sk = elu1(h@Wk^T)
    gemm_bt<<<gproj, blk, 0, stream>>>(h, w_v, v,  M, D, D, 0);  // v  = h@Wv^T
    gemm_bn<<<gproj, blk, 0, stream>>>(sq, memory, comb, M, D, D);   // comb = sq@memory
    mem_combine<<<M / 4, blk, 0, stream>>>(sq, mnorm, gate, comb);   // comb *= g*active/norm

    // parallel chunk scan
    chunk_kv<<<dim3(D / 64, D / 64, Bv * NCH), blk, 0, stream>>>(sk, v, Pst, zst);
    scan_P<<<(Bv * D * D) / 256, blk, 0, stream>>>(Pst);
    scan_z<<<(Bv * D) / 256, blk, 0, stream>>>(zst);
    attn_scores_all<<<dim3(CH / 64, CH / 64, Bv * NCH), blk, 0, stream>>>(sq, sk, Abuf);
    attn_den_all<<<(Bv * S) / 4, blk, 0, stream>>>(Abuf, sq, zst, den);
    attn_out_all<<<dim3(D / 64, CH / 64, Bv * NCH), blk, 0, stream>>>(Abuf, v, sq, Pst, den, gate, comb);

    gemm_bt<<<gproj, blk, 0, stream>>>(comb, w_o, out, M, D, D, 0);  // out = comb@Wo^T
}

// Round 4
// 397.507 us; speedup vs baseline: 7.5315x; 2.7765x over previous
//
#include <hip/hip_runtime.h>
#include <cstddef>

#define EPSF 1e-6f

constexpr int D   = 1024;
constexpr int Bv  = 2;
constexpr int S   = 2048;
constexpr int M   = Bv * S;    // 4096
constexpr int CH  = 256;       // chunk
constexpr int NCH = S / CH;    // 8

typedef __attribute__((ext_vector_type(8))) short short8;   // 8 bf16 (4 VGPRs)
typedef __attribute__((ext_vector_type(4))) float floatx4;  // 4 fp32 acc

__device__ __forceinline__ float elu1(float x) { return x > 0.f ? x + 1.f : __expf(x); }
__device__ __forceinline__ float sigmoidf_(float x) { return 1.f / (1.f + __expf(-x)); }
__device__ __forceinline__ unsigned short f2bf(float x) {
    unsigned u = __float_as_uint(x);
    return (unsigned short)((u + 0x7fffu + ((u >> 16) & 1u)) >> 16);
}
__device__ __forceinline__ float bf2f(unsigned short h) {
    return __uint_as_float(((unsigned)h) << 16);
}
__device__ __forceinline__ float wave_reduce(float x) {
#pragma unroll
    for (int off = 32; off > 0; off >>= 1) x += __shfl_down(x, off);
    return x;
}

// async global->LDS, 16B per lane, LDS dest = wave-uniform base + lane*16
__device__ __forceinline__ void gl_lds16(const unsigned short* g, unsigned short* l) {
    __builtin_amdgcn_global_load_lds(
        (const __attribute__((address_space(1))) void*)g,
        (__attribute__((address_space(3))) void*)l, 16, 0, 0);
}

// stage a 128x32 bf16 tile (row stride `stride` elems) into LDS as linear row-major [128][32]
__device__ __forceinline__ void stage128x32(const unsigned short* g, int stride,
                                            unsigned short* lds, int wave, int lane) {
    const int t   = (wave << 6) + lane;
    const int row = t >> 2;            // byte t*16 -> row t/4
    const int cb  = (t & 3) << 3;      // elem offset within 32-elem row
    unsigned short* l0 = lds + (wave << 9);   // wave covers 1024 B per load
    gl_lds16(g + (size_t)row * stride + cb, l0);
    gl_lds16(g + (size_t)(row + 64) * stride + cb, l0 + 2048);
}

// 16 MFMAs on the staged tiles; A-frag: A[m=lane&15][k=quad*8+j], same for B (B^T form)
__device__ __forceinline__ void mfma_step(const unsigned short* As, const unsigned short* Bs,
                                          int wm, int wn, int fr, int fo, floatx4 acc[4][4]) {
    short8 af[4], bf[4];
#pragma unroll
    for (int i = 0; i < 4; ++i) af[i] = *(const short8*)&As[(wm + i * 16 + fr) * 32 + fo];
#pragma unroll
    for (int j = 0; j < 4; ++j) bf[j] = *(const short8*)&Bs[(wn + j * 16 + fr) * 32 + fo];
#pragma unroll
    for (int i = 0; i < 4; ++i)
#pragma unroll
        for (int j = 0; j < 4; ++j)
            acc[i][j] = __builtin_amdgcn_mfma_f32_16x16x32_bf16(af[i], bf[j], acc[i][j], 0, 0, 0);
}

// full K-loop: C_tile(128x128) += A[128 rows, K] . B[128 rows, K]^T  (both K-contiguous)
__device__ __forceinline__ void gemm_loop(const unsigned short* Ag, int strideA,
                                          const unsigned short* Bg, int strideB, int Kk,
                                          unsigned short* As, unsigned short* Bs,
                                          int wave, int lane, int wm, int wn, int fr, int fo,
                                          floatx4 acc[4][4]) {
    for (int k0 = 0; k0 < Kk; k0 += 32) {
        __syncthreads();
        stage128x32(Ag + k0, strideA, As, wave, lane);
        stage128x32(Bg + k0, strideB, Bs, wave, lane);
        __syncthreads();
        mfma_step(As, Bs, wm, wn, fr, fo, acc);
    }
}

// C[M,N] = A[M,K] @ B[N,K]^T. mode 0: fp32 store; 1: bf16+elu1; 2: bf16 plain.
__global__ __launch_bounds__(256) void gemm_bf16(const unsigned short* __restrict__ A,
                                                 const unsigned short* __restrict__ B,
                                                 float* __restrict__ Cf,
                                                 unsigned short* __restrict__ Cb,
                                                 int Kk, int Nn, int mode)
{
    __shared__ unsigned short As[128 * 32], Bs[128 * 32];
    const int tid = threadIdx.x, wave = tid >> 6, lane = tid & 63;
    const int m0 = blockIdx.y * 128, n0 = blockIdx.x * 128;
    const int wm = (wave >> 1) * 64, wn = (wave & 1) * 64;
    const int fr = lane & 15, fo = (lane >> 4) * 8;
    const int q4 = (lane >> 4) * 4;

    floatx4 acc[4][4] = {};
    gemm_loop(A + (size_t)m0 * Kk, Kk, B + (size_t)n0 * Kk, Kk, Kk,
              As, Bs, wave, lane, wm, wn, fr, fo, acc);

#pragma unroll
    for (int i = 0; i < 4; ++i)
#pragma unroll
        for (int j = 0; j < 4; ++j) {
            const int col = n0 + wn + j * 16 + fr;
#pragma unroll
            for (int r = 0; r < 4; ++r) {
                const int row = m0 + wm + i * 16 + q4 + r;
                float v = acc[i][j][r];
                if (mode == 0)      Cf[(size_t)row * Nn + col] = v;
                else if (mode == 1) Cb[(size_t)row * Nn + col] = f2bf(elu1(v));
                else                Cb[(size_t)row * Nn + col] = f2bf(v);
            }
        }
}

// Abuf[bc] = tril(sq_c @ sk_c^T) in bf16. grid (CH/128, CH/128, Bv*NCH)
__global__ __launch_bounds__(256) void scores_m(const unsigned short* __restrict__ sq,
                                                const unsigned short* __restrict__ sk,
                                                unsigned short* __restrict__ Abuf)
{
    const int bc = blockIdx.z, b = bc / NCH, c = bc % NCH;
    const int it = blockIdx.y, jt = blockIdx.x;
    unsigned short* Cp = Abuf + (size_t)bc * CH * CH;
    const int tid = threadIdx.x;

    if (jt > it) {  // fully above diagonal: zero-fill, skip compute
        const size_t base = (size_t)(it * 128 + (tid >> 1)) * CH + jt * 128 + (tid & 1) * 64;
        uint4 z4 = make_uint4(0, 0, 0, 0);
#pragma unroll
        for (int i = 0; i < 8; ++i) *(uint4*)(Cp + base + i * 8) = z4;
        return;
    }

    __shared__ unsigned short As[128 * 32], Bs[128 * 32];
    const int wave = tid >> 6, lane = tid & 63;
    const int wm = (wave >> 1) * 64, wn = (wave & 1) * 64;
    const int fr = lane & 15, fo = (lane >> 4) * 8;
    const int q4 = (lane >> 4) * 4;
    const unsigned short* qbase = sq + ((size_t)b * S + (size_t)c * CH) * D;
    const unsigned short* kbase = sk + ((size_t)b * S + (size_t)c * CH) * D;

    floatx4 acc[4][4] = {};
    gemm_loop(qbase + (size_t)(it * 128) * D, D, kbase + (size_t)(jt * 128) * D, D, D,
              As, Bs, wave, lane, wm, wn, fr, fo, acc);

#pragma unroll
    for (int i = 0; i < 4; ++i)
#pragma unroll
        for (int j = 0; j < 4; ++j) {
            const int col = jt * 128 + wn + j * 16 + fr;
#pragma unroll
            for (int r = 0; r < 4; ++r) {
                const int row = it * 128 + wm + i * 16 + q4 + r;
                float v = (col <= row) ? acc[i][j][r] : 0.f;
                Cp[(size_t)row * CH + col] = f2bf(v);
            }
        }
}

// PT[bc][e][d] = sum_m vT[b][e][cCH+m] * skT[b][d][cCH+m]  (= (sk_c^T v_c)^T)
// grid (D/128 d-tiles, D/128 e-tiles, Bv*NCH)
__global__ __launch_bounds__(256) void chunk_kv_m(const unsigned short* __restrict__ vT,
                                                  const unsigned short* __restrict__ skT,
                                                  unsigned short* __restrict__ PT)
{
    __shared__ unsigned short As[128 * 32], Bs[128 * 32];
    const int bc = blockIdx.z, b = bc / NCH, c = bc % NCH;
    const int tid = threadIdx.x, wave = tid >> 6, lane = tid & 63;
    const int e0 = blockIdx.y * 128, d0 = blockIdx.x * 128;
    const int wm = (wave >> 1) * 64, wn = (wave & 1) * 64;
    const int fr = lane & 15, fo = (lane >> 4) * 8;
    const int q4 = (lane >> 4) * 4;

    const unsigned short* Ag = vT + (size_t)b * D * S + (size_t)e0 * S + c * CH;
    const unsigned short* Bg = skT + (size_t)b * D * S + (size_t)d0 * S + c * CH;

    floatx4 acc[4][4] = {};
    gemm_loop(Ag, S, Bg, S, CH, As, Bs, wave, lane, wm, wn, fr, fo, acc);

    unsigned short* Cp = PT + (size_t)bc * D * D;
#pragma unroll
    for (int i = 0; i < 4; ++i)
#pragma unroll
        for (int j = 0; j < 4; ++j) {
            const int col = d0 + wn + j * 16 + fr;
#pragma unroll
            for (int r = 0; r < 4; ++r) {
                const int row = e0 + wm + i * 16 + q4 + r;
                Cp[(size_t)row * D + col] = f2bf(acc[i][j][r]);
            }
        }
}

// comb[r,:] += (1-g) * (Abuf@v_c + sq@P_prefix) / clip(den), via two B^T-form phases
// grid (D/128 e-tiles, CH/128 i-tiles, Bv*NCH)
__global__ __launch_bounds__(256) void attn_out_m(const unsigned short* __restrict__ Abuf,
                                                  const unsigned short* __restrict__ vT,
                                                  const unsigned short* __restrict__ sq,
                                                  const unsigned short* __restrict__ PT,
                                                  const float* __restrict__ den,
                                                  const float* __restrict__ gate,
                                                  float* __restrict__ comb)
{
    __shared__ unsigned short As[128 * 32], Bs[128 * 32];
    const int bc = blockIdx.z, b = bc / NCH, c = bc % NCH;
    const int tid = threadIdx.x, wave = tid >> 6, lane = tid & 63;
    const int e0 = blockIdx.x * 128, i0 = blockIdx.y * 128;
    const int wm = (wave >> 1) * 64, wn = (wave & 1) * 64;
    const int fr = lane & 15, fo = (lane >> 4) * 8;
    const int q4 = (lane >> 4) * 4;

    floatx4 acc[4][4] = {};
    // phase 1: A = Abuf rows i (K=CH), B = vT rows e (k = c*CH+j)
    gemm_loop(Abuf + (size_t)bc * CH * CH + (size_t)i0 * CH, CH,
              vT + (size_t)b * D * S + (size_t)e0 * S + c * CH, S, CH,
              As, Bs, wave, lane, wm, wn, fr, fo, acc);
    // phase 2: A = sq rows (K=D), B = PT rows e (k = d)
    gemm_loop(sq + ((size_t)b * S + c * CH + i0) * D, D,
              PT + (size_t)bc * D * D + (size_t)e0 * D, D, D,
              As, Bs, wave, lane, wm, wn, fr, fo, acc);

    const float g = sigmoidf_(gate[0]);
    const float wloc = 1.f - g;
#pragma unroll
    for (int i = 0; i < 4; ++i)
#pragma unroll
        for (int j = 0; j < 4; ++j) {
            const int col = e0 + wn + j * 16 + fr;
#pragma unroll
            for (int r = 0; r < 4; ++r) {
                const int li = i0 + wm + i * 16 + q4 + r;        // row within chunk
                const int rg = b * S + c * CH + li;              // global row
                const float inv = wloc / fmaxf(den[rg], EPSF);
                comb[(size_t)rg * D + col] += acc[i][j][r] * inv;
            }
        }
}

// fp32 -> bf16 convert, 4 elems/thread
__global__ __launch_bounds__(256) void cvt_f2b(const float* __restrict__ in,
                                               unsigned short* __restrict__ out)
{
    const size_t i = ((size_t)blockIdx.x * 256 + threadIdx.x) * 4;
    float4 v = *(const float4*)(in + i);
    ushort4 o;
    o.x = f2bf(v.x); o.y = f2bf(v.y); o.z = f2bf(v.z); o.w = f2bf(v.w);
    *(ushort4*)(out + i) = o;
}

// memory fp32 [D][D] -> memT bf16 [e][d]  (transpose+convert), 64x64 tiles
__global__ __launch_bounds__(256) void transpose_cvt(const float* __restrict__ in,
                                                     unsigned short* __restrict__ out)
{
    __shared__ unsigned short T[64][72];
    const int d0 = blockIdx.y * 64, e0 = blockIdx.x * 64;
    const int tid = threadIdx.x;
    const int r = tid >> 4, c4 = (tid & 15) * 4;
    for (int rr = r; rr < 64; rr += 16) {
        float4 v = *(const float4*)(in + (size_t)(d0 + rr) * D + e0 + c4);
        T[rr][c4 + 0] = f2bf(v.x); T[rr][c4 + 1] = f2bf(v.y);
        T[rr][c4 + 2] = f2bf(v.z); T[rr][c4 + 3] = f2bf(v.w);
    }
    __syncthreads();
    for (int rr = r; rr < 64; rr += 16) {
        ushort4 o;
        o.x = T[c4 + 0][rr]; o.y = T[c4 + 1][rr];
        o.z = T[c4 + 2][rr]; o.w = T[c4 + 3][rr];
        *(ushort4*)(out + (size_t)(e0 + rr) * D + d0 + c4) = o;
    }
}

// bf16 [b][S][D] -> [b][D][S], 64x64 tiles. grid (D/64, S/64, Bv)
__global__ __launch_bounds__(256) void transpose_b(const unsigned short* __restrict__ in,
                                                   unsigned short* __restrict__ out)
{
    __shared__ unsigned short T[64][72];
    const int b = blockIdx.z;
    const int s0 = blockIdx.y * 64, d0 = blockIdx.x * 64;
    const int tid = threadIdx.x;
    const int r = tid >> 4, c4 = (tid & 15) * 4;
    const unsigned short* ip = in + (size_t)b * S * D;
    for (int rr = r; rr < 64; rr += 16) {
        ushort4 v = *(const ushort4*)(ip + (size_t)(s0 + rr) * D + d0 + c4);
        T[rr][c4 + 0] = v.x; T[rr][c4 + 1] = v.y; T[rr][c4 + 2] = v.z; T[rr][c4 + 3] = v.w;
    }
    __syncthreads();
    unsigned short* op = out + (size_t)b * D * S;
    for (int rr = r; rr < 64; rr += 16) {
        ushort4 o;
        o.x = T[c4 + 0][rr]; o.y = T[c4 + 1][rr];
        o.z = T[c4 + 2][rr]; o.w = T[c4 + 3][rr];
        *(ushort4*)(op + (size_t)(d0 + rr) * S + s0 + c4) = o;
    }
}

// z_c[bc][d] = sum_{m in chunk} skT[b][d][m]
__global__ __launch_bounds__(256) void colsum_z(const unsigned short* __restrict__ skT,
                                                float* __restrict__ zst)
{
    const int g = blockIdx.x * 256 + threadIdx.x;   // 0 .. Bv*NCH*D-1
    const int bc = g / D, d = g % D;
    const int b = bc / NCH, c = bc % NCH;
    const unsigned short* p = skT + (size_t)b * D * S + (size_t)d * S + c * CH;
    float s = 0.f;
    for (int m = 0; m < CH; m += 4) {
        ushort4 v = *(const ushort4*)(p + m);
        s += bf2f(v.x) + bf2f(v.y) + bf2f(v.z) + bf2f(v.w);
    }
    zst[g] = s;
}

// in-place exclusive prefix over chunks (bf16 values, fp32 accum)
__global__ __launch_bounds__(256) void scan_P(unsigned short* __restrict__ PT)
{
    const size_t g = (size_t)blockIdx.x * 256 + threadIdx.x;   // 0 .. Bv*D*D-1
    const int b = (int)(g / ((size_t)D * D));
    const size_t idx = g % ((size_t)D * D);
    unsigned short* p = PT + (size_t)b * NCH * D * D + idx;
    float acc = 0.f;
#pragma unroll
    for (int c = 0; c < NCH; ++c) {
        unsigned short* q = p + (size_t)c * D * D;
        float tmp = bf2f(*q);
        *q = f2bf(acc);
        acc += tmp;
    }
}

__global__ __launch_bounds__(256) void scan_z(float* __restrict__ zst)
{
    const int g = blockIdx.x * 256 + threadIdx.x;   // 0 .. Bv*D-1
    const int b = g / D, d = g % D;
    float* p = zst + (size_t)b * NCH * D + d;
    float acc = 0.f;
#pragma unroll
    for (int c = 0; c < NCH; ++c) {
        float tmp = p[(size_t)c * D];
        p[(size_t)c * D] = acc;
        acc += tmp;
    }
}

// den[r] = rowsum(Abuf row) + sq_r . z_prefix
__global__ __launch_bounds__(256) void den_all(const unsigned short* __restrict__ Abuf,
                                               const unsigned short* __restrict__ sq,
                                               const float* __restrict__ zst,
                                               float* __restrict__ den)
{
    const int wave = threadIdx.x >> 6, lane = threadIdx.x & 63;
    const int r = blockIdx.x * 4 + wave;
    const int b = r / S, sr = r % S, c = sr / CH, i = sr % CH;
    const unsigned short* Ar = Abuf + ((size_t)(b * NCH + c) * CH + i) * CH;
    ushort4 a4 = *(const ushort4*)(Ar + lane * 4);
    float s = bf2f(a4.x) + bf2f(a4.y) + bf2f(a4.z) + bf2f(a4.w);
    const unsigned short* Sq = sq + (size_t)r * D;
    const float* zb = zst + (size_t)(b * NCH + c) * D;
    for (int d0 = lane * 4; d0 < D; d0 += 256) {
        ushort4 q4 = *(const ushort4*)(Sq + d0);
        float4 z4 = *(const float4*)(zb + d0);
        s += bf2f(q4.x) * z4.x + bf2f(q4.y) * z4.y + bf2f(q4.z) * z4.z + bf2f(q4.w) * z4.w;
    }
    s = wave_reduce(s);
    if (lane == 0) den[r] = s;
}

// comb[row,:] *= g*active / clip(sq_row . mnorm, EPS)
__global__ __launch_bounds__(256) void mem_combine(const unsigned short* __restrict__ sq,
                                                   const float* __restrict__ mnorm,
                                                   const float* __restrict__ gate,
                                                   float* __restrict__ comb)
{
    const int wave = threadIdx.x >> 6, lane = threadIdx.x & 63;
    const int row = blockIdx.x * 4 + wave;
    const unsigned short* sr = sq + (size_t)row * D;
    float dot = 0.f, msum = 0.f;
    for (int d = lane; d < D; d += 64) {
        float mn = mnorm[d];
        dot += bf2f(sr[d]) * mn;
        msum += mn;
    }
    dot = wave_reduce(dot);
    msum = wave_reduce(msum);
    dot = __shfl(dot, 0);
    msum = __shfl(msum, 0);
    const float g = sigmoidf_(gate[0]);
    const float active = (msum >= EPSF) ? 1.f : 0.f;
    const float scale = g * active / fmaxf(dot, EPSF);
    float* cr = comb + (size_t)row * D;
    for (int e = lane; e < D; e += 64) cr[e] *= scale;
}

extern "C" void kernel_launch(void* const* d_in, const int* in_sizes, int n_in,
                              void* d_out, int out_size, void* d_ws, size_t ws_size,
                              hipStream_t stream)
{
    const float* h      = (const float*)d_in[0];
    const float* w_q    = (const float*)d_in[1];
    const float* w_k    = (const float*)d_in[2];
    const float* w_v    = (const float*)d_in[3];
    const float* w_o    = (const float*)d_in[4];
    const float* gate   = (const float*)d_in[5];
    const float* memory = (const float*)d_in[6];
    const float* mnorm  = (const float*)d_in[7];
    float* out = (float*)d_out;

    // ---- workspace layout (~92 MB), with dead-buffer aliasing ----
    // h_b is reused as vT after projections; wq_b..memT region is reused as skT;
    // v_b is reused as comb_b at the end.
    unsigned short* h_b  = (unsigned short*)d_ws;           // M*D bf16 (8 MB), later vT
    unsigned short* wq_b = h_b + (size_t)M * D;             // D*D (2 MB), later skT part
    unsigned short* wk_b = wq_b + (size_t)D * D;            // D*D
    unsigned short* wv_b = wk_b + (size_t)D * D;            // D*D
    unsigned short* memT = wv_b + (size_t)D * D;            // D*D
    unsigned short* wo_b = memT + (size_t)D * D;            // D*D (live to end)
    unsigned short* sq_b = wo_b + (size_t)D * D;            // M*D (8 MB)
    unsigned short* sk_b = sq_b + (size_t)M * D;            // M*D (8 MB)
    unsigned short* v_b  = sk_b + (size_t)M * D;            // M*D (8 MB), later comb_b
    unsigned short* PT   = v_b + (size_t)M * D;             // Bv*NCH*D*D (32 MB)
    unsigned short* Abuf = PT + (size_t)Bv * NCH * D * D;   // Bv*NCH*CH*CH (2 MB)
    float* comb = (float*)(Abuf + (size_t)Bv * NCH * CH * CH);  // M*D fp32 (16 MB)
    float* den  = comb + (size_t)M * D;                     // M
    float* zst  = den + M;                                  // Bv*NCH*D
    unsigned short* vT     = h_b;
    unsigned short* skT    = wq_b;
    unsigned short* comb_b = v_b;

    dim3 blk(256);
    dim3 gbig(8, 32);   // N/128 x M/128 for the 4096x1024x1024 GEMMs

    // converts
    cvt_f2b<<<(size_t)M * D / 1024, blk, 0, stream>>>(h, h_b);
    cvt_f2b<<<(size_t)D * D / 1024, blk, 0, stream>>>(w_q, wq_b);
    cvt_f2b<<<(size_t)D * D / 1024, blk, 0, stream>>>(w_k, wk_b);
    cvt_f2b<<<(size_t)D * D / 1024, blk, 0, stream>>>(w_v, wv_b);
    cvt_f2b<<<(size_t)D * D / 1024, blk, 0, stream>>>(w_o, wo_b);
    transpose_cvt<<<dim3(D / 64, D / 64), blk, 0, stream>>>(memory, memT);

    // projections (MFMA): sq = elu1(h@Wq^T) bf16, sk likewise, v plain bf16
    gemm_bf16<<<gbig, blk, 0, stream>>>(h_b, wq_b, nullptr, sq_b, D, D, 1);
    gemm_bf16<<<gbig, blk, 0, stream>>>(h_b, wk_b, nullptr, sk_b, D, D, 1);
    gemm_bf16<<<gbig, blk, 0, stream>>>(h_b, wv_b, nullptr, v_b, D, D, 2);

    // memory path: comb = sq@memory (fp32), then scale by g*active/norm
    gemm_bf16<<<gbig, blk, 0, stream>>>(sq_b, memT, comb, nullptr, D, D, 0);
    mem_combine<<<M / 4, blk, 0, stream>>>(sq_b, mnorm, gate, comb);

    // transposes (after projections/gemm_mem: h_b and wq..memT are dead)
    transpose_b<<<dim3(D / 64, S / 64, Bv), blk, 0, stream>>>(v_b, vT);
    transpose_b<<<dim3(D / 64, S / 64, Bv), blk, 0, stream>>>(sk_b, skT);

    // chunk scan
    chunk_kv_m<<<dim3(D / 128, D / 128, Bv * NCH), blk, 0, stream>>>(vT, skT, PT);
    colsum_z<<<(Bv * NCH * D) / 256, blk, 0, stream>>>(skT, zst);
    scan_P<<<((size_t)Bv * D * D) / 256, blk, 0, stream>>>(PT);
    scan_z<<<(Bv * D) / 256, blk, 0, stream>>>(zst);

    // intra-chunk attention
    scores_m<<<dim3(CH / 128, CH / 128, Bv * NCH), blk, 0, stream>>>(sq_b, sk_b, Abuf);
    den_all<<<M / 4, blk, 0, stream>>>(Abuf, sq_b, zst, den);
    attn_out_m<<<dim3(D / 128, CH / 128, Bv * NCH), blk, 0, stream>>>(Abuf, vT, sq_b, PT, den, gate, comb);

    // output projection
    cvt_f2b<<<(size_t)M * D / 1024, blk, 0, stream>>>(comb, comb_b);
    gemm_bf16<<<gbig, blk, 0, stream>>>(comb_b, wo_b, out, nullptr, D, D, 0);
}

// Round 6
// 294.454 us; speedup vs baseline: 10.1674x; 1.3500x over previous
//
#include <hip/hip_runtime.h>
#include <cstddef>

#define EPSF 1e-6f

constexpr int D   = 1024;
constexpr int Bv  = 2;
constexpr int S   = 2048;
constexpr int M   = Bv * S;    // 4096
constexpr int CH  = 256;       // chunk
constexpr int NCH = S / CH;    // 8

constexpr int TSZ = 128 * 32;  // one LDS tile buffer (elems)

typedef __attribute__((ext_vector_type(8))) short short8;   // 8 bf16 (4 VGPRs)
typedef __attribute__((ext_vector_type(4))) float floatx4;  // 4 fp32 acc

__device__ __forceinline__ float elu1(float x) { return x > 0.f ? x + 1.f : __expf(x); }
__device__ __forceinline__ float sigmoidf_(float x) { return 1.f / (1.f + __expf(-x)); }
__device__ __forceinline__ unsigned short f2bf(float x) {
    unsigned u = __float_as_uint(x);
    return (unsigned short)((u + 0x7fffu + ((u >> 16) & 1u)) >> 16);
}
__device__ __forceinline__ float bf2f(unsigned short h) {
    return __uint_as_float(((unsigned)h) << 16);
}
__device__ __forceinline__ float wave_reduce(float x) {
#pragma unroll
    for (int off = 32; off > 0; off >>= 1) x += __shfl_down(x, off);
    return x;
}

// async global->LDS, 16B per lane, LDS dest = wave-uniform base + lane*16
__device__ __forceinline__ void gl_lds16(const unsigned short* g, unsigned short* l) {
    __builtin_amdgcn_global_load_lds(
        (const __attribute__((address_space(1))) void*)g,
        (__attribute__((address_space(3))) void*)l, 16, 0, 0);
}

// stage a 128x32 bf16 tile (row stride in elems) into LDS as linear row-major [128][32]
__device__ __forceinline__ void stage128x32(const unsigned short* g, int stride,
                                            unsigned short* lds, int wave, int lane) {
    const int t   = (wave << 6) + lane;
    const int row = t >> 2;            // byte t*16 -> row t/4
    const int cb  = (t & 3) << 3;      // elem offset within 32-elem row
    unsigned short* l0 = lds + (wave << 9);   // wave covers 1024 B per load
    gl_lds16(g + (size_t)row * stride + cb, l0);
    gl_lds16(g + (size_t)(row + 64) * stride + cb, l0 + 2048);
}

// 16 MFMAs on staged tiles; A-frag: A[m=lane&15][k=quad*8+j], same for B (B^T form)
__device__ __forceinline__ void mfma_step(const unsigned short* As, const unsigned short* Bs,
                                          int wm, int wn, int fr, int fo, floatx4 acc[4][4]) {
    short8 af[4], bf[4];
#pragma unroll
    for (int i = 0; i < 4; ++i) af[i] = *(const short8*)&As[(wm + i * 16 + fr) * 32 + fo];
#pragma unroll
    for (int j = 0; j < 4; ++j) bf[j] = *(const short8*)&Bs[(wn + j * 16 + fr) * 32 + fo];
#pragma unroll
    for (int i = 0; i < 4; ++i)
#pragma unroll
        for (int j = 0; j < 4; ++j)
            acc[i][j] = __builtin_amdgcn_mfma_f32_16x16x32_bf16(af[i], bf[j], acc[i][j], 0, 0, 0);
}

// Double-buffered K-loop: C_tile(128x128) += A[128,K] . B[128,K]^T (both K-contiguous).
// One barrier per iter; stage(k+1) is in flight while MFMA runs on tile k.
// As/Bs are 2*TSZ each. Leading __syncthreads protects LDS reuse across calls.
__device__ __forceinline__ void gemm_loop_db(const unsigned short* Ag, int strideA,
                                             const unsigned short* Bg, int strideB, int Kk,
                                             unsigned short* As, unsigned short* Bs,
                                             int wave, int lane, int wm, int wn, int fr, int fo,
                                             floatx4 acc[4][4]) {
    __syncthreads();   // all waves done with any previous LDS contents
    stage128x32(Ag, strideA, As, wave, lane);
    stage128x32(Bg, strideB, Bs, wave, lane);
    int buf = 0;
    for (int k0 = 32; k0 < Kk; k0 += 32) {
        __syncthreads();                       // drains stage of buf (vmcnt0 at barrier)
        const int nb = buf ^ 1;
        stage128x32(Ag + k0, strideA, As + nb * TSZ, wave, lane);
        stage128x32(Bg + k0, strideB, Bs + nb * TSZ, wave, lane);
        mfma_step(As + buf * TSZ, Bs + buf * TSZ, wm, wn, fr, fo, acc);
        buf = nb;
    }
    __syncthreads();
    mfma_step(As + buf * TSZ, Bs + buf * TSZ, wm, wn, fr, fo, acc);
}

// Fused q/k/v projections. grid 768 linear blocks: sub = id/256 (0:q 1:k 2:v)
__global__ __launch_bounds__(256) void proj_fused(const unsigned short* __restrict__ h_b,
                                                  const unsigned short* __restrict__ wq,
                                                  const unsigned short* __restrict__ wk,
                                                  const unsigned short* __restrict__ wv,
                                                  unsigned short* __restrict__ sq,
                                                  unsigned short* __restrict__ sk,
                                                  unsigned short* __restrict__ v)
{
    __shared__ unsigned short As[2 * TSZ], Bs[2 * TSZ];
    const int id = blockIdx.x;
    const int sub = id >> 8, t = id & 255;
    const int m0 = (t >> 3) * 128, n0 = (t & 7) * 128;
    const unsigned short* B = (sub == 0) ? wq : (sub == 1) ? wk : wv;
    unsigned short* C = (sub == 0) ? sq : (sub == 1) ? sk : v;

    const int tid = threadIdx.x, wave = tid >> 6, lane = tid & 63;
    const int wm = (wave >> 1) * 64, wn = (wave & 1) * 64;
    const int fr = lane & 15, fo = (lane >> 4) * 8;
    const int q4 = (lane >> 4) * 4;

    floatx4 acc[4][4] = {};
    gemm_loop_db(h_b + (size_t)m0 * D, D, B + (size_t)n0 * D, D, D,
                 As, Bs, wave, lane, wm, wn, fr, fo, acc);

#pragma unroll
    for (int i = 0; i < 4; ++i)
#pragma unroll
        for (int j = 0; j < 4; ++j) {
            const int col = n0 + wn + j * 16 + fr;
#pragma unroll
            for (int r = 0; r < 4; ++r) {
                const int row = m0 + wm + i * 16 + q4 + r;
                float val = acc[i][j][r];
                if (sub < 2) val = elu1(val);
                C[(size_t)row * D + col] = f2bf(val);
            }
        }
}

// Fused {chunk_kv (1024 blocks) + mem-gemm (256) + scores (64)} = 1344 linear blocks
__global__ __launch_bounds__(256) void big_fused(const unsigned short* __restrict__ sq,
                                                 const unsigned short* __restrict__ sk,
                                                 const unsigned short* __restrict__ memT,
                                                 const unsigned short* __restrict__ vT,
                                                 const unsigned short* __restrict__ skT,
                                                 float* __restrict__ comb,
                                                 unsigned short* __restrict__ Abuf,
                                                 unsigned short* __restrict__ PT)
{
    __shared__ unsigned short As[2 * TSZ], Bs[2 * TSZ];
    const int id = blockIdx.x;
    const int tid = threadIdx.x, wave = tid >> 6, lane = tid & 63;
    const int wm = (wave >> 1) * 64, wn = (wave & 1) * 64;
    const int fr = lane & 15, fo = (lane >> 4) * 8;
    const int q4 = (lane >> 4) * 4;

    floatx4 acc[4][4] = {};

    if (id < 1024) {
        // chunk_kv: PT[bc][e][d] = sum_m vT[b][e][cCH+m]*skT[b][d][cCH+m]
        const int bc = id >> 6, rem = id & 63;
        const int b = bc >> 3, c = bc & 7;               // NCH == 8
        const int e0 = (rem >> 3) * 128, d0 = (rem & 7) * 128;
        gemm_loop_db(vT + (size_t)b * D * S + (size_t)e0 * S + c * CH, S,
                     skT + (size_t)b * D * S + (size_t)d0 * S + c * CH, S, CH,
                     As, Bs, wave, lane, wm, wn, fr, fo, acc);
        unsigned short* Cp = PT + (size_t)bc * D * D;
#pragma unroll
        for (int i = 0; i < 4; ++i)
#pragma unroll
            for (int j = 0; j < 4; ++j) {
                const int col = d0 + wn + j * 16 + fr;
#pragma unroll
                for (int r = 0; r < 4; ++r)
                    Cp[(size_t)(e0 + wm + i * 16 + q4 + r) * D + col] = f2bf(acc[i][j][r]);
            }
    } else if (id < 1280) {
        // mem-gemm: comb = sq @ memT^T (memT rows are columns of memory)
        const int t = id - 1024;
        const int m0 = (t >> 3) * 128, n0 = (t & 7) * 128;
        gemm_loop_db(sq + (size_t)m0 * D, D, memT + (size_t)n0 * D, D, D,
                     As, Bs, wave, lane, wm, wn, fr, fo, acc);
#pragma unroll
        for (int i = 0; i < 4; ++i)
#pragma unroll
            for (int j = 0; j < 4; ++j) {
                const int col = n0 + wn + j * 16 + fr;
#pragma unroll
                for (int r = 0; r < 4; ++r)
                    comb[(size_t)(m0 + wm + i * 16 + q4 + r) * D + col] = acc[i][j][r];
            }
    } else {
        // scores: Abuf[bc] = tril(sq_c @ sk_c^T)
        const int t = id - 1280;
        const int bc = t >> 2, it = (t >> 1) & 1, jt = t & 1;
        const int b = bc >> 3, c = bc & 7;
        unsigned short* Cp = Abuf + (size_t)bc * CH * CH;
        if (jt > it) {  // fully above diagonal: zero-fill
            const size_t base = (size_t)(it * 128 + (tid >> 1)) * CH + jt * 128 + (tid & 1) * 64;
            uint4 z4 = make_uint4(0, 0, 0, 0);
#pragma unroll
            for (int i = 0; i < 8; ++i) *(uint4*)(Cp + base + i * 8) = z4;
            return;
        }
        const unsigned short* qb = sq + ((size_t)b * S + (size_t)c * CH + it * 128) * D;
        const unsigned short* kb = sk + ((size_t)b * S + (size_t)c * CH + jt * 128) * D;
        gemm_loop_db(qb, D, kb, D, D, As, Bs, wave, lane, wm, wn, fr, fo, acc);
#pragma unroll
        for (int i = 0; i < 4; ++i)
#pragma unroll
            for (int j = 0; j < 4; ++j) {
                const int col = jt * 128 + wn + j * 16 + fr;
#pragma unroll
                for (int r = 0; r < 4; ++r) {
                    const int row = it * 128 + wm + i * 16 + q4 + r;
                    float v = (col <= row) ? acc[i][j][r] : 0.f;
                    Cp[(size_t)row * CH + col] = f2bf(v);
                }
            }
    }
}

// comb[r,:] += (1-g) * (Abuf@v_c + sq@P_prefix) / clip(den)  — grid (8, 2, 16)
__global__ __launch_bounds__(256) void attn_out_m(const unsigned short* __restrict__ Abuf,
                                                  const unsigned short* __restrict__ vT,
                                                  const unsigned short* __restrict__ sq,
                                                  const unsigned short* __restrict__ PT,
                                                  const float* __restrict__ den,
                                                  const float* __restrict__ gate,
                                                  float* __restrict__ comb)
{
    __shared__ unsigned short As[2 * TSZ], Bs[2 * TSZ];
    const int bc = blockIdx.z, b = bc / NCH, c = bc % NCH;
    const int tid = threadIdx.x, wave = tid >> 6, lane = tid & 63;
    const int e0 = blockIdx.x * 128, i0 = blockIdx.y * 128;
    const int wm = (wave >> 1) * 64, wn = (wave & 1) * 64;
    const int fr = lane & 15, fo = (lane >> 4) * 8;
    const int q4 = (lane >> 4) * 4;

    floatx4 acc[4][4] = {};
    // phase 1: A = Abuf rows i (K=CH), B = vT rows e
    gemm_loop_db(Abuf + (size_t)bc * CH * CH + (size_t)i0 * CH, CH,
                 vT + (size_t)b * D * S + (size_t)e0 * S + c * CH, S, CH,
                 As, Bs, wave, lane, wm, wn, fr, fo, acc);
    // phase 2: A = sq rows (K=D), B = PT rows e
    gemm_loop_db(sq + ((size_t)b * S + c * CH + i0) * D, D,
                 PT + (size_t)bc * D * D + (size_t)e0 * D, D, D,
                 As, Bs, wave, lane, wm, wn, fr, fo, acc);

    const float g = sigmoidf_(gate[0]);
    const float wloc = 1.f - g;
#pragma unroll
    for (int i = 0; i < 4; ++i)
#pragma unroll
        for (int j = 0; j < 4; ++j) {
            const int col = e0 + wn + j * 16 + fr;
#pragma unroll
            for (int r = 0; r < 4; ++r) {
                const int li = i0 + wm + i * 16 + q4 + r;
                const int rg = b * S + c * CH + li;
                const float inv = wloc / fmaxf(den[rg], EPSF);
                comb[(size_t)rg * D + col] += acc[i][j][r] * inv;
            }
        }
}

// Generic B^T GEMM (used for out-proj), fp32 store.
__global__ __launch_bounds__(256) void gemm_bf16(const unsigned short* __restrict__ A,
                                                 const unsigned short* __restrict__ B,
                                                 float* __restrict__ Cf,
                                                 int Kk, int Nn)
{
    __shared__ unsigned short As[2 * TSZ], Bs[2 * TSZ];
    const int tid = threadIdx.x, wave = tid >> 6, lane = tid & 63;
    const int m0 = blockIdx.y * 128, n0 = blockIdx.x * 128;
    const int wm = (wave >> 1) * 64, wn = (wave & 1) * 64;
    const int fr = lane & 15, fo = (lane >> 4) * 8;
    const int q4 = (lane >> 4) * 4;

    floatx4 acc[4][4] = {};
    gemm_loop_db(A + (size_t)m0 * Kk, Kk, B + (size_t)n0 * Kk, Kk, Kk,
                 As, Bs, wave, lane, wm, wn, fr, fo, acc);

#pragma unroll
    for (int i = 0; i < 4; ++i)
#pragma unroll
        for (int j = 0; j < 4; ++j) {
            const int col = n0 + wn + j * 16 + fr;
#pragma unroll
            for (int r = 0; r < 4; ++r)
                Cf[(size_t)(m0 + wm + i * 16 + q4 + r) * Nn + col] = acc[i][j][r];
        }
}

// fp32 -> bf16 convert, 4 elems/thread
__global__ __launch_bounds__(256) void cvt_f2b(const float* __restrict__ in,
                                               unsigned short* __restrict__ out)
{
    const size_t i = ((size_t)blockIdx.x * 256 + threadIdx.x) * 4;
    float4 v = *(const float4*)(in + i);
    ushort4 o;
    o.x = f2bf(v.x); o.y = f2bf(v.y); o.z = f2bf(v.z); o.w = f2bf(v.w);
    *(ushort4*)(out + i) = o;
}

// 4 weight matrices (D*D each) fp32->bf16 in one dispatch; grid 4*1024 blocks
__global__ __launch_bounds__(256) void cvt_w4(const float* __restrict__ a, const float* __restrict__ b,
                                              const float* __restrict__ c, const float* __restrict__ d,
                                              unsigned short* __restrict__ oa, unsigned short* __restrict__ ob,
                                              unsigned short* __restrict__ oc, unsigned short* __restrict__ od)
{
    const int which = blockIdx.x >> 10;
    const float* in = (which == 0) ? a : (which == 1) ? b : (which == 2) ? c : d;
    unsigned short* out = (which == 0) ? oa : (which == 1) ? ob : (which == 2) ? oc : od;
    const size_t i = ((size_t)(blockIdx.x & 1023) * 256 + threadIdx.x) * 4;
    float4 v = *(const float4*)(in + i);
    ushort4 o;
    o.x = f2bf(v.x); o.y = f2bf(v.y); o.z = f2bf(v.z); o.w = f2bf(v.w);
    *(ushort4*)(out + i) = o;
}

// memory fp32 [D][D] -> memT bf16 [e][d] (transpose+convert), 64x64 tiles
__global__ __launch_bounds__(256) void transpose_cvt(const float* __restrict__ in,
                                                     unsigned short* __restrict__ out)
{
    __shared__ unsigned short T[64][72];
    const int d0 = blockIdx.y * 64, e0 = blockIdx.x * 64;
    const int tid = threadIdx.x;
    const int r = tid >> 4, c4 = (tid & 15) * 4;
    for (int rr = r; rr < 64; rr += 16) {
        float4 v = *(const float4*)(in + (size_t)(d0 + rr) * D + e0 + c4);
        T[rr][c4 + 0] = f2bf(v.x); T[rr][c4 + 1] = f2bf(v.y);
        T[rr][c4 + 2] = f2bf(v.z); T[rr][c4 + 3] = f2bf(v.w);
    }
    __syncthreads();
    for (int rr = r; rr < 64; rr += 16) {
        ushort4 o;
        o.x = T[c4 + 0][rr]; o.y = T[c4 + 1][rr];
        o.z = T[c4 + 2][rr]; o.w = T[c4 + 3][rr];
        *(ushort4*)(out + (size_t)(e0 + rr) * D + d0 + c4) = o;
    }
}

// fused bf16 transposes: v_b->vT and sk_b->skT. grid (D/64, S/64, Bv*2)
__global__ __launch_bounds__(256) void transpose_fused(const unsigned short* __restrict__ v_b,
                                                       const unsigned short* __restrict__ sk_b,
                                                       unsigned short* __restrict__ vT,
                                                       unsigned short* __restrict__ skT)
{
    __shared__ unsigned short T[64][72];
    const int b = blockIdx.z >> 1, w = blockIdx.z & 1;
    const unsigned short* in = w ? sk_b : v_b;
    unsigned short* out = w ? skT : vT;
    const int s0 = blockIdx.y * 64, d0 = blockIdx.x * 64;
    const int tid = threadIdx.x;
    const int r = tid >> 4, c4 = (tid & 15) * 4;
    const unsigned short* ip = in + (size_t)b * S * D;
    for (int rr = r; rr < 64; rr += 16) {
        ushort4 v = *(const ushort4*)(ip + (size_t)(s0 + rr) * D + d0 + c4);
        T[rr][c4 + 0] = v.x; T[rr][c4 + 1] = v.y; T[rr][c4 + 2] = v.z; T[rr][c4 + 3] = v.w;
    }
    __syncthreads();
    unsigned short* op = out + (size_t)b * D * S;
    for (int rr = r; rr < 64; rr += 16) {
        ushort4 o;
        o.x = T[c4 + 0][rr]; o.y = T[c4 + 1][rr];
        o.z = T[c4 + 2][rr]; o.w = T[c4 + 3][rr];
        *(ushort4*)(op + (size_t)(d0 + rr) * S + s0 + c4) = o;
    }
}

// z_c[bc][d] = sum_{m in chunk} skT[b][d][m]
__global__ __launch_bounds__(256) void colsum_z(const unsigned short* __restrict__ skT,
                                                float* __restrict__ zst)
{
    const int g = blockIdx.x * 256 + threadIdx.x;
    const int bc = g / D, d = g % D;
    const int b = bc / NCH, c = bc % NCH;
    const unsigned short* p = skT + (size_t)b * D * S + (size_t)d * S + c * CH;
    float s = 0.f;
    for (int m = 0; m < CH; m += 4) {
        ushort4 v = *(const ushort4*)(p + m);
        s += bf2f(v.x) + bf2f(v.y) + bf2f(v.z) + bf2f(v.w);
    }
    zst[g] = s;
}

// in-place exclusive prefix over chunks (bf16 values, fp32 accum)
__global__ __launch_bounds__(256) void scan_P(unsigned short* __restrict__ PT)
{
    const size_t g = (size_t)blockIdx.x * 256 + threadIdx.x;
    const int b = (int)(g / ((size_t)D * D));
    const size_t idx = g % ((size_t)D * D);
    unsigned short* p = PT + (size_t)b * NCH * D * D + idx;
    float acc = 0.f;
#pragma unroll
    for (int c = 0; c < NCH; ++c) {
        unsigned short* q = p + (size_t)c * D * D;
        float tmp = bf2f(*q);
        *q = f2bf(acc);
        acc += tmp;
    }
}

__global__ __launch_bounds__(256) void scan_z(float* __restrict__ zst)
{
    const int g = blockIdx.x * 256 + threadIdx.x;
    const int b = g / D, d = g % D;
    float* p = zst + (size_t)b * NCH * D + d;
    float acc = 0.f;
#pragma unroll
    for (int c = 0; c < NCH; ++c) {
        float tmp = p[(size_t)c * D];
        p[(size_t)c * D] = acc;
        acc += tmp;
    }
}

// den[r] = rowsum(Abuf row) + sq_r . z_prefix
__global__ __launch_bounds__(256) void den_all(const unsigned short* __restrict__ Abuf,
                                               const unsigned short* __restrict__ sq,
                                               const float* __restrict__ zst,
                                               float* __restrict__ den)
{
    const int wave = threadIdx.x >> 6, lane = threadIdx.x & 63;
    const int r = blockIdx.x * 4 + wave;
    const int b = r / S, sr = r % S, c = sr / CH, i = sr % CH;
    const unsigned short* Ar = Abuf + ((size_t)(b * NCH + c) * CH + i) * CH;
    ushort4 a4 = *(const ushort4*)(Ar + lane * 4);
    float s = bf2f(a4.x) + bf2f(a4.y) + bf2f(a4.z) + bf2f(a4.w);
    const unsigned short* Sq = sq + (size_t)r * D;
    const float* zb = zst + (size_t)(b * NCH + c) * D;
    for (int d0 = lane * 4; d0 < D; d0 += 256) {
        ushort4 q4 = *(const ushort4*)(Sq + d0);
        float4 z4 = *(const float4*)(zb + d0);
        s += bf2f(q4.x) * z4.x + bf2f(q4.y) * z4.y + bf2f(q4.z) * z4.z + bf2f(q4.w) * z4.w;
    }
    s = wave_reduce(s);
    if (lane == 0) den[r] = s;
}

// comb[row,:] *= g*active / clip(sq_row . mnorm, EPS)
__global__ __launch_bounds__(256) void mem_combine(const unsigned short* __restrict__ sq,
                                                   const float* __restrict__ mnorm,
                                                   const float* __restrict__ gate,
                                                   float* __restrict__ comb)
{
    const int wave = threadIdx.x >> 6, lane = threadIdx.x & 63;
    const int row = blockIdx.x * 4 + wave;
    const unsigned short* sr = sq + (size_t)row * D;
    float dot = 0.f, msum = 0.f;
    for (int d = lane; d < D; d += 64) {
        float mn = mnorm[d];
        dot += bf2f(sr[d]) * mn;
        msum += mn;
    }
    dot = wave_reduce(dot);
    msum = wave_reduce(msum);
    dot = __shfl(dot, 0);
    msum = __shfl(msum, 0);
    const float g = sigmoidf_(gate[0]);
    const float active = (msum >= EPSF) ? 1.f : 0.f;
    const float scale = g * active / fmaxf(dot, EPSF);
    float* cr = comb + (size_t)row * D;
    for (int e = lane; e < D; e += 64) cr[e] *= scale;
}

extern "C" void kernel_launch(void* const* d_in, const int* in_sizes, int n_in,
                              void* d_out, int out_size, void* d_ws, size_t ws_size,
                              hipStream_t stream)
{
    const float* h      = (const float*)d_in[0];
    const float* w_q    = (const float*)d_in[1];
    const float* w_k    = (const float*)d_in[2];
    const float* w_v    = (const float*)d_in[3];
    const float* w_o    = (const float*)d_in[4];
    const float* gate   = (const float*)d_in[5];
    const float* memory = (const float*)d_in[6];
    const float* mnorm  = (const float*)d_in[7];
    float* out = (float*)d_out;

    // ---- workspace layout (~94 MB) ----
    // ALIASING RULES (the round-5 bug was skT clobbering memT):
    //   vT   aliases h_b            (h_b dead after proj_fused)
    //   skT  aliases {wq,wk,wv,pad} (weights dead after proj_fused; memT NOT in this span)
    //   comb_b aliases v_b          (v_b dead after big_fused/attn use via vT)
    //   memT has its own slot, live through big_fused.
    unsigned short* h_b  = (unsigned short*)d_ws;             // M*D bf16 (8 MB), later vT
    unsigned short* wq_b = h_b + (size_t)M * D;               // D*D (2 MB) } skT span
    unsigned short* wk_b = wq_b + (size_t)D * D;              // D*D        } skT span
    unsigned short* wv_b = wk_b + (size_t)D * D;              // D*D        } skT span
    // (D*D pad completes the 8 MB skT span)
    unsigned short* memT = wq_b + 4 * (size_t)D * D;          // D*D (2 MB), own slot
    unsigned short* wo_b = memT + (size_t)D * D;              // D*D (2 MB, live to end)
    unsigned short* sq_b = wo_b + (size_t)D * D;              // M*D (8 MB)
    unsigned short* sk_b = sq_b + (size_t)M * D;              // M*D (8 MB)
    unsigned short* v_b  = sk_b + (size_t)M * D;              // M*D (8 MB), later comb_b
    unsigned short* PT   = v_b + (size_t)M * D;               // Bv*NCH*D*D (32 MB)
    unsigned short* Abuf = PT + (size_t)Bv * NCH * D * D;     // Bv*NCH*CH*CH (2 MB)
    float* comb = (float*)(Abuf + (size_t)Bv * NCH * CH * CH);// M*D fp32 (16 MB)
    float* den  = comb + (size_t)M * D;                       // M
    float* zst  = den + M;                                    // Bv*NCH*D
    unsigned short* vT     = h_b;
    unsigned short* skT    = wq_b;
    unsigned short* comb_b = v_b;

    dim3 blk(256);

    // converts (3 dispatches)
    cvt_f2b<<<(size_t)M * D / 1024, blk, 0, stream>>>(h, h_b);
    cvt_w4<<<4 * 1024, blk, 0, stream>>>(w_q, w_k, w_v, w_o, wq_b, wk_b, wv_b, wo_b);
    transpose_cvt<<<dim3(D / 64, D / 64), blk, 0, stream>>>(memory, memT);

    // fused projections: 768 blocks = 3 blocks/CU
    proj_fused<<<768, blk, 0, stream>>>(h_b, wq_b, wk_b, wv_b, sq_b, sk_b, v_b);

    // fused transposes: v_b->vT (aliases h_b), sk_b->skT (aliases wq..wv+pad)
    transpose_fused<<<dim3(D / 64, S / 64, Bv * 2), blk, 0, stream>>>(v_b, sk_b, vT, skT);

    // fused {chunk_kv + mem-gemm + scores}: 1344 blocks = 5.25 blocks/CU
    big_fused<<<1344, blk, 0, stream>>>(sq_b, sk_b, memT, vT, skT, comb, Abuf, PT);

    // small scalar kernels
    mem_combine<<<M / 4, blk, 0, stream>>>(sq_b, mnorm, gate, comb);
    colsum_z<<<(Bv * NCH * D) / 256, blk, 0, stream>>>(skT, zst);
    scan_P<<<((size_t)Bv * D * D) / 256, blk, 0, stream>>>(PT);
    scan_z<<<(Bv * D) / 256, blk, 0, stream>>>(zst);
    den_all<<<M / 4, blk, 0, stream>>>(Abuf, sq_b, zst, den);

    // attention output accumulation
    attn_out_m<<<dim3(D / 128, CH / 128, Bv * NCH), blk, 0, stream>>>(Abuf, vT, sq_b, PT, den, gate, comb);

    // output projection
    cvt_f2b<<<(size_t)M * D / 1024, blk, 0, stream>>>(comb, comb_b);
    gemm_bf16<<<dim3(8, 32), blk, 0, stream>>>(comb_b, wo_b, out, D, D);
}

// Round 7
// 251.793 us; speedup vs baseline: 11.8901x; 1.1694x over previous
//
#include <hip/hip_runtime.h>
#include <cstddef>

#define EPSF 1e-6f

constexpr int D   = 1024;
constexpr int Bv  = 2;
constexpr int S   = 2048;
constexpr int M   = Bv * S;    // 4096
constexpr int CH  = 256;       // chunk
constexpr int NCH = S / CH;    // 8
constexpr int NPAIR = NCH * (NCH + 1) / 2;   // 36 (j<=c)

constexpr int TSZ  = 128 * 32; // 128-row LDS tile (elems)
constexpr int TA64 = 64 * 32;  // 64-row LDS tile (elems)

typedef __attribute__((ext_vector_type(8))) short short8;   // 8 bf16
typedef __attribute__((ext_vector_type(4))) float floatx4;  // 4 fp32

__device__ __forceinline__ float elu1(float x) { return x > 0.f ? x + 1.f : __expf(x); }
__device__ __forceinline__ float sigmoidf_(float x) { return 1.f / (1.f + __expf(-x)); }
__device__ __forceinline__ unsigned short f2bf(float x) {
    unsigned u = __float_as_uint(x);
    return (unsigned short)((u + 0x7fffu + ((u >> 16) & 1u)) >> 16);
}
__device__ __forceinline__ float bf2f(unsigned short h) {
    return __uint_as_float(((unsigned)h) << 16);
}
__device__ __forceinline__ float wave_reduce(float x) {
#pragma unroll
    for (int off = 32; off > 0; off >>= 1) x += __shfl_down(x, off);
    return x;
}

// async global->LDS, 16B per lane, LDS dest = wave-uniform base + lane*16
__device__ __forceinline__ void gl_lds16(const unsigned short* g, unsigned short* l) {
    __builtin_amdgcn_global_load_lds(
        (const __attribute__((address_space(1))) void*)g,
        (__attribute__((address_space(3))) void*)l, 16, 0, 0);
}

// stage a 128x32 bf16 tile into LDS row-major [128][32]
__device__ __forceinline__ void stage128x32(const unsigned short* g, int stride,
                                            unsigned short* lds, int wave, int lane) {
    const int t   = (wave << 6) + lane;
    const int row = t >> 2;
    const int cb  = (t & 3) << 3;
    unsigned short* l0 = lds + (wave << 9);
    gl_lds16(g + (size_t)row * stride + cb, l0);
    gl_lds16(g + (size_t)(row + 64) * stride + cb, l0 + 2048);
}

// stage a 64x32 bf16 tile into LDS row-major [64][32] (one load per thread)
__device__ __forceinline__ void stage64x32(const unsigned short* g, int stride,
                                           unsigned short* lds, int wave, int lane) {
    const int t   = (wave << 6) + lane;
    const int row = t >> 2;
    const int cb  = (t & 3) << 3;
    gl_lds16(g + (size_t)row * stride + cb, lds + (wave << 9));
}

// 16 MFMAs, 128x128 tile, wave grid 2x2 (wm in {0,64}, wn in {0,64})
__device__ __forceinline__ void mfma_step(const unsigned short* As, const unsigned short* Bs,
                                          int wm, int wn, int fr, int fo, floatx4 acc[4][4]) {
    short8 af[4], bf[4];
#pragma unroll
    for (int i = 0; i < 4; ++i) af[i] = *(const short8*)&As[(wm + i * 16 + fr) * 32 + fo];
#pragma unroll
    for (int j = 0; j < 4; ++j) bf[j] = *(const short8*)&Bs[(wn + j * 16 + fr) * 32 + fo];
#pragma unroll
    for (int i = 0; i < 4; ++i)
#pragma unroll
        for (int j = 0; j < 4; ++j)
            acc[i][j] = __builtin_amdgcn_mfma_f32_16x16x32_bf16(af[i], bf[j], acc[i][j], 0, 0, 0);
}

// 8 MFMAs, 64x128 tile, wave grid 2x2 (wm in {0,32}, wn in {0,64})
__device__ __forceinline__ void mfma_step64(const unsigned short* As, const unsigned short* Bs,
                                            int wm, int wn, int fr, int fo, floatx4 acc[2][4]) {
    short8 af[2], bf[4];
#pragma unroll
    for (int i = 0; i < 2; ++i) af[i] = *(const short8*)&As[(wm + i * 16 + fr) * 32 + fo];
#pragma unroll
    for (int j = 0; j < 4; ++j) bf[j] = *(const short8*)&Bs[(wn + j * 16 + fr) * 32 + fo];
#pragma unroll
    for (int i = 0; i < 2; ++i)
#pragma unroll
        for (int j = 0; j < 4; ++j)
            acc[i][j] = __builtin_amdgcn_mfma_f32_16x16x32_bf16(af[i], bf[j], acc[i][j], 0, 0, 0);
}

// Double-buffered K-loop, 128x128 tile: C += A[128,K] . B[128,K]^T (both K-contiguous)
__device__ __forceinline__ void gemm_loop_db(const unsigned short* Ag, int strideA,
                                             const unsigned short* Bg, int strideB, int Kk,
                                             unsigned short* As, unsigned short* Bs,
                                             int wave, int lane, int wm, int wn, int fr, int fo,
                                             floatx4 acc[4][4]) {
    __syncthreads();
    stage128x32(Ag, strideA, As, wave, lane);
    stage128x32(Bg, strideB, Bs, wave, lane);
    int buf = 0;
    for (int k0 = 32; k0 < Kk; k0 += 32) {
        __syncthreads();
        const int nb = buf ^ 1;
        stage128x32(Ag + k0, strideA, As + nb * TSZ, wave, lane);
        stage128x32(Bg + k0, strideB, Bs + nb * TSZ, wave, lane);
        mfma_step(As + buf * TSZ, Bs + buf * TSZ, wm, wn, fr, fo, acc);
        buf = nb;
    }
    __syncthreads();
    mfma_step(As + buf * TSZ, Bs + buf * TSZ, wm, wn, fr, fo, acc);
}

// Double-buffered K-loop, 64x128 tile
__device__ __forceinline__ void gemm_loop_db64(const unsigned short* Ag, int strideA,
                                               const unsigned short* Bg, int strideB, int Kk,
                                               unsigned short* As, unsigned short* Bs,
                                               int wave, int lane, int wm, int wn, int fr, int fo,
                                               floatx4 acc[2][4]) {
    __syncthreads();
    stage64x32(Ag, strideA, As, wave, lane);
    stage128x32(Bg, strideB, Bs, wave, lane);
    int buf = 0;
    for (int k0 = 32; k0 < Kk; k0 += 32) {
        __syncthreads();
        const int nb = buf ^ 1;
        stage64x32(Ag + k0, strideA, As + nb * TA64, wave, lane);
        stage128x32(Bg + k0, strideB, Bs + nb * TSZ, wave, lane);
        mfma_step64(As + buf * TA64, Bs + buf * TSZ, wm, wn, fr, fo, acc);
        buf = nb;
    }
    __syncthreads();
    mfma_step64(As + buf * TA64, Bs + buf * TSZ, wm, wn, fr, fo, acc);
}

// ---------------- prep: cvt h (4096) + cvt 4 weights (4096) + transpose memory (256) ----------
__global__ __launch_bounds__(256) void prep(const float* __restrict__ h,
                                            const float* __restrict__ w_q, const float* __restrict__ w_k,
                                            const float* __restrict__ w_v, const float* __restrict__ w_o,
                                            const float* __restrict__ memory,
                                            unsigned short* __restrict__ h_b,
                                            unsigned short* __restrict__ wq_b, unsigned short* __restrict__ wk_b,
                                            unsigned short* __restrict__ wv_b, unsigned short* __restrict__ wo_b,
                                            unsigned short* __restrict__ memT)
{
    __shared__ unsigned short T[64][72];
    const int id = blockIdx.x, tid = threadIdx.x;
    if (id < 4096) {
        const size_t i = ((size_t)id * 256 + tid) * 4;
        float4 v = *(const float4*)(h + i);
        ushort4 o; o.x = f2bf(v.x); o.y = f2bf(v.y); o.z = f2bf(v.z); o.w = f2bf(v.w);
        *(ushort4*)(h_b + i) = o;
    } else if (id < 8192) {
        const int t = id - 4096, which = t >> 10;
        const float* in = (which == 0) ? w_q : (which == 1) ? w_k : (which == 2) ? w_v : w_o;
        unsigned short* out = (which == 0) ? wq_b : (which == 1) ? wk_b : (which == 2) ? wv_b : wo_b;
        const size_t i = ((size_t)(t & 1023) * 256 + tid) * 4;
        float4 v = *(const float4*)(in + i);
        ushort4 o; o.x = f2bf(v.x); o.y = f2bf(v.y); o.z = f2bf(v.z); o.w = f2bf(v.w);
        *(ushort4*)(out + i) = o;
    } else {
        const int t = id - 8192;             // 0..255
        const int d0 = (t >> 4) * 64, e0 = (t & 15) * 64;
        const int r = tid >> 4, c4 = (tid & 15) * 4;
        for (int rr = r; rr < 64; rr += 16) {
            float4 v = *(const float4*)(memory + (size_t)(d0 + rr) * D + e0 + c4);
            T[rr][c4 + 0] = f2bf(v.x); T[rr][c4 + 1] = f2bf(v.y);
            T[rr][c4 + 2] = f2bf(v.z); T[rr][c4 + 3] = f2bf(v.w);
        }
        __syncthreads();
        for (int rr = r; rr < 64; rr += 16) {
            ushort4 o;
            o.x = T[c4 + 0][rr]; o.y = T[c4 + 1][rr];
            o.z = T[c4 + 2][rr]; o.w = T[c4 + 3][rr];
            *(ushort4*)(memT + (size_t)(e0 + rr) * D + d0 + c4) = o;
        }
    }
}

// ---------------- fused q/k/v projections: 768 blocks ----------------
__global__ __launch_bounds__(256) void proj_fused(const unsigned short* __restrict__ h_b,
                                                  const unsigned short* __restrict__ wq,
                                                  const unsigned short* __restrict__ wk,
                                                  const unsigned short* __restrict__ wv,
                                                  unsigned short* __restrict__ sq,
                                                  unsigned short* __restrict__ sk,
                                                  unsigned short* __restrict__ v)
{
    __shared__ unsigned short As[2 * TSZ], Bs[2 * TSZ];
    const int id = blockIdx.x;
    const int sub = id >> 8, t = id & 255;
    const int m0 = (t >> 3) * 128, n0 = (t & 7) * 128;
    const unsigned short* B = (sub == 0) ? wq : (sub == 1) ? wk : wv;
    unsigned short* C = (sub == 0) ? sq : (sub == 1) ? sk : v;

    const int tid = threadIdx.x, wave = tid >> 6, lane = tid & 63;
    const int wm = (wave >> 1) * 64, wn = (wave & 1) * 64;
    const int fr = lane & 15, fo = (lane >> 4) * 8;
    const int q4 = (lane >> 4) * 4;

    floatx4 acc[4][4] = {};
    gemm_loop_db(h_b + (size_t)m0 * D, D, B + (size_t)n0 * D, D, D,
                 As, Bs, wave, lane, wm, wn, fr, fo, acc);

#pragma unroll
    for (int i = 0; i < 4; ++i)
#pragma unroll
        for (int j = 0; j < 4; ++j) {
            const int col = n0 + wn + j * 16 + fr;
#pragma unroll
            for (int r = 0; r < 4; ++r) {
                const int row = m0 + wm + i * 16 + q4 + r;
                float val = acc[i][j][r];
                if (sub < 2) val = elu1(val);
                C[(size_t)row * D + col] = f2bf(val);
            }
        }
}

// ---------------- stage2: memgemm(256) + scores all pairs(288) + transpose_v(1024) ----------------
// Sbuf layout: [b][pair p=c(c+1)/2+j][256][256] bf16
__global__ __launch_bounds__(256) void stage2(const unsigned short* __restrict__ sq,
                                              const unsigned short* __restrict__ sk,
                                              const unsigned short* __restrict__ memT,
                                              const unsigned short* __restrict__ v_b,
                                              float* __restrict__ comb,
                                              unsigned short* __restrict__ Sbuf,
                                              unsigned short* __restrict__ vT)
{
    __shared__ unsigned short As[2 * TSZ], Bs[2 * TSZ];
    const int id = blockIdx.x, tid = threadIdx.x;
    const int wave = tid >> 6, lane = tid & 63;
    const int wm = (wave >> 1) * 64, wn = (wave & 1) * 64;
    const int fr = lane & 15, fo = (lane >> 4) * 8;
    const int q4 = (lane >> 4) * 4;

    if (id < 256) {
        // comb = sq @ memT^T (fp32)
        const int m0 = (id >> 3) * 128, n0 = (id & 7) * 128;
        floatx4 acc[4][4] = {};
        gemm_loop_db(sq + (size_t)m0 * D, D, memT + (size_t)n0 * D, D, D,
                     As, Bs, wave, lane, wm, wn, fr, fo, acc);
#pragma unroll
        for (int i = 0; i < 4; ++i)
#pragma unroll
            for (int j = 0; j < 4; ++j) {
                const int col = n0 + wn + j * 16 + fr;
#pragma unroll
                for (int r = 0; r < 4; ++r)
                    comb[(size_t)(m0 + wm + i * 16 + q4 + r) * D + col] = acc[i][j][r];
            }
    } else if (id < 544) {
        // scores pair (c,j): S_cj = sq_c @ sk_j^T, tril mask only on diagonal pair
        const int t = id - 256;
        const int b = t / 144, rem = t % 144;
        const int p = rem >> 2, tt = rem & 3;
        const int it = tt >> 1, jt = tt & 1;
        int c = 0;
        while ((c + 1) * (c + 2) / 2 <= p) ++c;
        const int j = p - c * (c + 1) / 2;
        unsigned short* Sp = Sbuf + ((size_t)(b * NPAIR + p) << 16);   // 256*256

        if (j == c && jt > it) {  // above diagonal: zero-fill
            const size_t base = (size_t)(it * 128 + (tid >> 1)) * CH + jt * 128 + (tid & 1) * 64;
            uint4 z4 = make_uint4(0, 0, 0, 0);
#pragma unroll
            for (int i = 0; i < 8; ++i) *(uint4*)(Sp + base + i * 8) = z4;
            return;
        }
        floatx4 acc[4][4] = {};
        gemm_loop_db(sq + ((size_t)b * S + (size_t)c * CH + it * 128) * D, D,
                     sk + ((size_t)b * S + (size_t)j * CH + jt * 128) * D, D, D,
                     As, Bs, wave, lane, wm, wn, fr, fo, acc);
        const bool diag = (j == c && it == jt);
#pragma unroll
        for (int i = 0; i < 4; ++i)
#pragma unroll
            for (int jj = 0; jj < 4; ++jj) {
                const int col = jt * 128 + wn + jj * 16 + fr;
#pragma unroll
                for (int r = 0; r < 4; ++r) {
                    const int row = it * 128 + wm + i * 16 + q4 + r;
                    float val = acc[i][jj][r];
                    if (diag && col > row) val = 0.f;
                    Sp[(size_t)row * CH + col] = f2bf(val);
                }
            }
    } else {
        // transpose v_b [b][s][d] -> vT [b][d][s], 64x64 tiles
        unsigned short (*T)[72] = (unsigned short(*)[72])As;
        const int t = id - 544;                    // 0..1023
        const int b = t >> 9, rem = t & 511;
        const int s0 = (rem >> 4) * 64, d0 = (rem & 15) * 64;
        const int r = tid >> 4, c4 = (tid & 15) * 4;
        const unsigned short* ip = v_b + (size_t)b * S * D;
        for (int rr = r; rr < 64; rr += 16) {
            ushort4 vv = *(const ushort4*)(ip + (size_t)(s0 + rr) * D + d0 + c4);
            T[rr][c4 + 0] = vv.x; T[rr][c4 + 1] = vv.y; T[rr][c4 + 2] = vv.z; T[rr][c4 + 3] = vv.w;
        }
        __syncthreads();
        unsigned short* op = vT + (size_t)b * D * S;
        for (int rr = r; rr < 64; rr += 16) {
            ushort4 o;
            o.x = T[c4 + 0][rr]; o.y = T[c4 + 1][rr];
            o.z = T[c4 + 2][rr]; o.w = T[c4 + 3][rr];
            *(ushort4*)(op + (size_t)(d0 + rr) * S + s0 + c4) = o;
        }
    }
}

// ---------------- epi1: mem_combine (1024) + den rowsum (1024) ----------------
__global__ __launch_bounds__(256) void epi1(const unsigned short* __restrict__ sq,
                                            const float* __restrict__ mnorm,
                                            const float* __restrict__ gate,
                                            const unsigned short* __restrict__ Sbuf,
                                            float* __restrict__ comb,
                                            float* __restrict__ den)
{
    const int id = blockIdx.x;
    const int wave = threadIdx.x >> 6, lane = threadIdx.x & 63;
    if (id < 1024) {
        // comb[row,:] *= g*active / clip(sq_row . mnorm, EPS)
        const int row = id * 4 + wave;
        const unsigned short* sr = sq + (size_t)row * D;
        float dot = 0.f, msum = 0.f;
        for (int d = lane; d < D; d += 64) {
            float mn = mnorm[d];
            dot += bf2f(sr[d]) * mn;
            msum += mn;
        }
        dot = wave_reduce(dot);
        msum = wave_reduce(msum);
        dot = __shfl(dot, 0);
        msum = __shfl(msum, 0);
        const float g = sigmoidf_(gate[0]);
        const float active = (msum >= EPSF) ? 1.f : 0.f;
        const float scale = g * active / fmaxf(dot, EPSF);
        float* cr = comb + (size_t)row * D;
        for (int e = lane; e < D; e += 64) cr[e] *= scale;
    } else {
        // den[r] = rowsum over all j<=c of S_cj[i,:]
        const int r = (id - 1024) * 4 + wave;
        const int b = r / S, sr_ = r % S, c = sr_ >> 8, i = sr_ & 255;
        const int pbase = c * (c + 1) / 2;
        float s = 0.f;
        for (int j = 0; j <= c; ++j) {
            const unsigned short* rp = Sbuf + ((size_t)(b * NPAIR + pbase + j) << 16) + (size_t)i * CH;
            ushort4 a4 = *(const ushort4*)(rp + lane * 4);
            s += bf2f(a4.x) + bf2f(a4.y) + bf2f(a4.z) + bf2f(a4.w);
        }
        s = wave_reduce(s);
        if (lane == 0) den[r] = s;
    }
}

// ---------------- pv: comb_b = f2bf(comb + (1-g)*(S @ v)/den), 512 blocks (64x128 tiles) --------
__global__ __launch_bounds__(256) void pv64(const unsigned short* __restrict__ Sbuf,
                                            const unsigned short* __restrict__ vT,
                                            const float* __restrict__ den,
                                            const float* __restrict__ gate,
                                            const float* __restrict__ comb,
                                            unsigned short* __restrict__ comb_b)
{
    __shared__ unsigned short As2[2 * TA64], Bs2[2 * TSZ];
    const int id = blockIdx.x, tid = threadIdx.x;
    const int wave = tid >> 6, lane = tid & 63;
    const int wm = (wave >> 1) * 32, wn = (wave & 1) * 64;
    const int fr = lane & 15, fo = (lane >> 4) * 8;
    const int q4 = (lane >> 4) * 4;

    const int bc = id >> 5, rem = id & 31;
    const int b = bc >> 3;
    const int c = (NCH - 1) - (bc & 7);           // long-K blocks first
    const int i0 = (rem >> 3) * 64, e0 = (rem & 7) * 128;
    const int pbase = c * (c + 1) / 2;

    floatx4 acc[2][4] = {};
    for (int j = 0; j <= c; ++j) {
        gemm_loop_db64(Sbuf + ((size_t)(b * NPAIR + pbase + j) << 16) + (size_t)i0 * CH, CH,
                       vT + (size_t)b * D * S + (size_t)e0 * S + j * CH, S, CH,
                       As2, Bs2, wave, lane, wm, wn, fr, fo, acc);
    }

    const float g = sigmoidf_(gate[0]);
    const float wloc = 1.f - g;
#pragma unroll
    for (int i = 0; i < 2; ++i)
#pragma unroll
        for (int j = 0; j < 4; ++j) {
            const int col = e0 + wn + j * 16 + fr;
#pragma unroll
            for (int r = 0; r < 4; ++r) {
                const int li = i0 + wm + i * 16 + q4 + r;       // row within chunk
                const int rg = b * S + c * CH + li;             // global row
                const float inv = wloc / fmaxf(den[rg], EPSF);
                const size_t idx = (size_t)rg * D + col;
                comb_b[idx] = f2bf(comb[idx] + acc[i][j][r] * inv);
            }
        }
}

// ---------------- out-proj: out = comb_b @ wo^T (fp32), 512 blocks (64x128 tiles) ----------------
__global__ __launch_bounds__(256) void outproj64(const unsigned short* __restrict__ A,
                                                 const unsigned short* __restrict__ wo,
                                                 float* __restrict__ out)
{
    __shared__ unsigned short As2[2 * TA64], Bs2[2 * TSZ];
    const int id = blockIdx.x, tid = threadIdx.x;
    const int wave = tid >> 6, lane = tid & 63;
    const int wm = (wave >> 1) * 32, wn = (wave & 1) * 64;
    const int fr = lane & 15, fo = (lane >> 4) * 8;
    const int q4 = (lane >> 4) * 4;
    const int m0 = (id >> 3) * 64, n0 = (id & 7) * 128;

    floatx4 acc[2][4] = {};
    gemm_loop_db64(A + (size_t)m0 * D, D, wo + (size_t)n0 * D, D, D,
                   As2, Bs2, wave, lane, wm, wn, fr, fo, acc);

#pragma unroll
    for (int i = 0; i < 2; ++i)
#pragma unroll
        for (int j = 0; j < 4; ++j) {
            const int col = n0 + wn + j * 16 + fr;
#pragma unroll
            for (int r = 0; r < 4; ++r)
                out[(size_t)(m0 + wm + i * 16 + q4 + r) * D + col] = acc[i][j][r];
        }
}

extern "C" void kernel_launch(void* const* d_in, const int* in_sizes, int n_in,
                              void* d_out, int out_size, void* d_ws, size_t ws_size,
                              hipStream_t stream)
{
    const float* h      = (const float*)d_in[0];
    const float* w_q    = (const float*)d_in[1];
    const float* w_k    = (const float*)d_in[2];
    const float* w_v    = (const float*)d_in[3];
    const float* w_o    = (const float*)d_in[4];
    const float* gate   = (const float*)d_in[5];
    const float* memory = (const float*)d_in[6];
    const float* mnorm  = (const float*)d_in[7];
    float* out = (float*)d_out;

    // ---- workspace layout (~84 MB), NO aliasing ----
    unsigned short* h_b    = (unsigned short*)d_ws;              // M*D (8 MB)
    unsigned short* wq_b   = h_b + (size_t)M * D;                // D*D
    unsigned short* wk_b   = wq_b + (size_t)D * D;               // D*D
    unsigned short* wv_b   = wk_b + (size_t)D * D;               // D*D
    unsigned short* wo_b   = wv_b + (size_t)D * D;               // D*D (8 MB total weights)
    unsigned short* memT   = wo_b + (size_t)D * D;               // D*D (2 MB)
    unsigned short* sq_b   = memT + (size_t)D * D;               // M*D (8 MB)
    unsigned short* sk_b   = sq_b + (size_t)M * D;               // M*D (8 MB)
    unsigned short* v_b    = sk_b + (size_t)M * D;               // M*D (8 MB)
    unsigned short* vT     = v_b + (size_t)M * D;                // M*D (8 MB)
    unsigned short* Sbuf   = vT + (size_t)M * D;                 // Bv*36*256*256 (9.4 MB)
    unsigned short* comb_b = Sbuf + (size_t)Bv * NPAIR * CH * CH;// M*D (8 MB)
    float* comb = (float*)(comb_b + (size_t)M * D);              // M*D fp32 (16 MB)
    float* den  = comb + (size_t)M * D;                          // M fp32

    dim3 blk(256);

    // 1. converts + memory transpose
    prep<<<8448, blk, 0, stream>>>(h, w_q, w_k, w_v, w_o, memory,
                                   h_b, wq_b, wk_b, wv_b, wo_b, memT);
    // 2. q/k/v projections (768 blocks = 3/CU)
    proj_fused<<<768, blk, 0, stream>>>(h_b, wq_b, wk_b, wv_b, sq_b, sk_b, v_b);
    // 3. mem-gemm + all score pairs + v transpose (1568 blocks)
    stage2<<<1568, blk, 0, stream>>>(sq_b, sk_b, memT, v_b, comb, Sbuf, vT);
    // 4. mem_combine + den (2048 blocks)
    epi1<<<2048, blk, 0, stream>>>(sq_b, mnorm, gate, Sbuf, comb, den);
    // 5. PV with fused combine + bf16 convert (512 blocks)
    pv64<<<512, blk, 0, stream>>>(Sbuf, vT, den, gate, comb, comb_b);
    // 6. output projection (512 blocks)
    outproj64<<<512, blk, 0, stream>>>(comb_b, wo_b, out);
}